// Round 9
// baseline (386.582 us; speedup 1.0000x reference)
//
#include <hip/hip_runtime.h>
#include <hip/hip_bf16.h>
#include <math.h>

#define NODES 30000
#define WAVE 64
#define SCAN_T 1024
#define SCAN_CH 32
#define SCAN_CAP (SCAN_T * SCAN_CH)   // 32768 >= NODES, branchless scan

typedef __attribute__((ext_vector_type(8))) short short8b;   // 8 bf16 (4 VGPRs)
typedef __attribute__((ext_vector_type(4))) float floatx4;   // MFMA C/D

static __device__ __forceinline__ float lrelu(float x) {
    return (x > 0.f) ? x : 0.2f * x;
}

// fp32 -> bf16 round-to-nearest-even
static __device__ __forceinline__ unsigned short f2bf(float f) {
    union { float f; unsigned u; } v; v.f = f;
    unsigned r = v.u + 0x7FFF + ((v.u >> 16) & 1);
    return (unsigned short)(r >> 16);
}

// unpack 8 bf16 (uint4) -> 8 floats
static __device__ __forceinline__ void unpack8(uint4 q, float* v) {
    v[0] = __uint_as_float(q.x << 16); v[1] = __uint_as_float(q.x & 0xFFFF0000u);
    v[2] = __uint_as_float(q.y << 16); v[3] = __uint_as_float(q.y & 0xFFFF0000u);
    v[4] = __uint_as_float(q.z << 16); v[5] = __uint_as_float(q.z & 0xFFFF0000u);
    v[6] = __uint_as_float(q.w << 16); v[7] = __uint_as_float(q.w & 0xFFFF0000u);
}

// pack 8 floats -> 8 bf16 (uint4)
static __device__ __forceinline__ uint4 pack8(const float* v) {
    uint4 p;
    p.x = (unsigned)f2bf(v[0]) | ((unsigned)f2bf(v[1]) << 16);
    p.y = (unsigned)f2bf(v[2]) | ((unsigned)f2bf(v[3]) << 16);
    p.z = (unsigned)f2bf(v[4]) | ((unsigned)f2bf(v[5]) << 16);
    p.w = (unsigned)f2bf(v[6]) | ((unsigned)f2bf(v[7]) << 16);
    return p;
}

// ---------------------------------------------------------------------------
// Fused prep (GAT path): zero deg + dots buffers, cvt weights & x to bf16.
// ---------------------------------------------------------------------------
__global__ __launch_bounds__(256) void prep(
    int* __restrict__ deg,
    float* __restrict__ z0, float* __restrict__ z1,
    float* __restrict__ z2, float* __restrict__ z3,
    const float* __restrict__ W1, unsigned short* __restrict__ wb1,
    const float* __restrict__ W2, unsigned short* __restrict__ wb2,
    const float* __restrict__ W3, unsigned short* __restrict__ wb3,
    const float* __restrict__ W4, unsigned short* __restrict__ wb4,
    const float* __restrict__ x, unsigned short* __restrict__ xb,
    const int* __restrict__ flag)
{
    if (*flag == 0) return;
    const int tid = blockIdx.x * blockDim.x + threadIdx.x;
    const int stride = gridDim.x * blockDim.x;
    for (int i = tid; i < SCAN_CAP / 4; i += stride)
        reinterpret_cast<int4*>(deg)[i] = make_int4(0, 0, 0, 0);
    for (int i = tid; i < NODES; i += stride) {
        z0[i] = 0.f; z1[i] = 0.f; z2[i] = 0.f; z3[i] = 0.f;
    }
    for (int i = tid; i < 256 * 64; i += stride) wb1[i] = f2bf(W1[i]);
    for (int i = tid; i < 32 * 256; i += stride) wb2[i] = f2bf(W2[i]);
    for (int i = tid; i < 256 * 32; i += stride) wb3[i] = f2bf(W3[i]);
    for (int i = tid; i < 64 * 256; i += stride) wb4[i] = f2bf(W4[i]);
    for (int i = tid; i < NODES * 64 / 4; i += stride) {
        float4 v = reinterpret_cast<const float4*>(x)[i];
        ushort4 o;
        o.x = f2bf(v.x); o.y = f2bf(v.y); o.z = f2bf(v.z); o.w = f2bf(v.w);
        reinterpret_cast<ushort4*>(xb)[i] = o;
    }
}

// ---------------------------------------------------------------------------
// MFMA GEMM: out[n, z*M + ct*16 + c] = Xb[n, z*K + k] @ Wb[z*M + m, k]^T
// bf16 in, fp32 accumulate. One 16x16 C tile per wave, LDS-free.
// C frag: col = lane&15, row = (lane>>4)*4 + i  (m89-verified).
// Optional fused attention dots (heads==1) via atomics on zeroed buffers.
// ---------------------------------------------------------------------------
template <int K, int M, int OUT_BF16, int RELU, int DOTS>
__global__ __launch_bounds__(256) void gemm_mfma(
    const unsigned short* __restrict__ Xb, int ldx,
    const unsigned short* __restrict__ Wb,
    const float* __restrict__ bias,
    void* __restrict__ outv, int ldc,
    const float* __restrict__ att_s, const float* __restrict__ att_d,
    float* __restrict__ as_out, float* __restrict__ ad_out,
    const int* __restrict__ flag, int Nrows)
{
    if (*flag == 0) return;
    constexpr int KC = K / 32;
    const int w    = threadIdx.x >> 6;
    const int lane = threadIdx.x & 63;
    const int z    = blockIdx.z;
    const int ct   = blockIdx.y;
    const int rowBase = blockIdx.x * 64 + w * 16;

    const int lr = lane & 15;
    const int lk = (lane >> 4) * 8;

    const int arow = min(rowBase + lr, Nrows - 1);
    const unsigned short* ap = Xb + (size_t)arow * ldx + z * K + lk;
    short8b a[KC];
#pragma unroll
    for (int kc = 0; kc < KC; kc++)
        a[kc] = *reinterpret_cast<const short8b*>(ap + kc * 32);

    const unsigned short* bp = Wb + (size_t)(z * M + ct * 16 + lr) * K + lk;
    short8b b[KC];
#pragma unroll
    for (int kc = 0; kc < KC; kc++)
        b[kc] = *reinterpret_cast<const short8b*>(bp + kc * 32);

    floatx4 c = {0.f, 0.f, 0.f, 0.f};
#pragma unroll
    for (int kc = 0; kc < KC; kc++)
        c = __builtin_amdgcn_mfma_f32_16x16x32_bf16(a[kc], b[kc], c, 0, 0, 0);

    const int colg = z * M + ct * 16 + lr;
    const float bv = bias ? bias[colg] : 0.f;

#pragma unroll
    for (int i = 0; i < 4; i++) {
        int r = rowBase + (lane >> 4) * 4 + i;
        float v = c[i] + bv;
        if (RELU) v = fmaxf(v, 0.f);
        if (r < Nrows) {
            if (OUT_BF16)
                ((unsigned short*)outv)[(size_t)r * ldc + colg] = f2bf(v);
            else
                ((float*)outv)[(size_t)r * ldc + colg] = v;
        }
    }

    if (DOTS) {  // partial row-dot over this tile's 16 cols (fp32 c) -> atomic
        const float as_v = att_s[colg];
        const float ad_v = att_d[colg];
#pragma unroll
        for (int i = 0; i < 4; i++) {
            int r = rowBase + (lane >> 4) * 4 + i;
            float ps = c[i] * as_v;
            float pd = c[i] * ad_v;
#pragma unroll
            for (int off = 8; off; off >>= 1) {
                ps += __shfl_xor(ps, off);
                pd += __shfl_xor(pd, off);
            }
            if (lr == 0 && r < Nrows) {
                atomicAdd(&as_out[r], ps);
                atomicAdd(&ad_out[r], pd);
            }
        }
    }
}

// ---------------------------------------------------------------------------
// fp32 GEMM (dense / use_neighbors==0 path only).
// ---------------------------------------------------------------------------
__global__ __launch_bounds__(256) void gemm_xwt(
    const float* __restrict__ X, int lda, const float* __restrict__ W,
    const float* __restrict__ bias, float* __restrict__ out, int ldc,
    int Nrows, int M, int K, int relu,
    const int* __restrict__ flag, int wantFlag)
{
    if (((*flag != 0) ? 1 : 0) != wantFlag) return;

    const int z = blockIdx.z;
    X += (size_t)z * K;
    W += (size_t)z * M * K;
    if (bias) bias += (size_t)z * M;
    out += (size_t)z * M;

    __shared__ float As[16][68];
    __shared__ float Bs[16][68];

    const int t  = threadIdx.x;
    const int tx = t & 15;
    const int ty = t >> 4;
    const int rowBase = blockIdx.y * 64;
    const int colBase = blockIdx.x * 64;

    float acc[4][4];
#pragma unroll
    for (int i = 0; i < 4; i++)
#pragma unroll
        for (int j = 0; j < 4; j++) acc[i][j] = 0.f;

    const int r_ld = t >> 2;
    const int k_ld = (t & 3) * 4;

    for (int kt = 0; kt < K; kt += 16) {
        float4 av = make_float4(0.f, 0.f, 0.f, 0.f);
        int grow = rowBase + r_ld;
        if (grow < Nrows)
            av = *reinterpret_cast<const float4*>(&X[(size_t)grow * lda + kt + k_ld]);
        As[k_ld + 0][r_ld] = av.x;
        As[k_ld + 1][r_ld] = av.y;
        As[k_ld + 2][r_ld] = av.z;
        As[k_ld + 3][r_ld] = av.w;
        float4 bv = make_float4(0.f, 0.f, 0.f, 0.f);
        int gm = colBase + r_ld;
        if (gm < M)
            bv = *reinterpret_cast<const float4*>(&W[(size_t)gm * K + kt + k_ld]);
        Bs[k_ld + 0][r_ld] = bv.x;
        Bs[k_ld + 1][r_ld] = bv.y;
        Bs[k_ld + 2][r_ld] = bv.z;
        Bs[k_ld + 3][r_ld] = bv.w;
        __syncthreads();

#pragma unroll
        for (int kk = 0; kk < 16; ++kk) {
            const float4 a = *reinterpret_cast<const float4*>(&As[kk][ty * 4]);
            const float4 b = *reinterpret_cast<const float4*>(&Bs[kk][tx * 4]);
            acc[0][0] += a.x * b.x; acc[0][1] += a.x * b.y; acc[0][2] += a.x * b.z; acc[0][3] += a.x * b.w;
            acc[1][0] += a.y * b.x; acc[1][1] += a.y * b.y; acc[1][2] += a.y * b.z; acc[1][3] += a.y * b.w;
            acc[2][0] += a.z * b.x; acc[2][1] += a.z * b.y; acc[2][2] += a.z * b.z; acc[2][3] += a.z * b.w;
            acc[3][0] += a.w * b.x; acc[3][1] += a.w * b.y; acc[3][2] += a.w * b.z; acc[3][3] += a.w * b.w;
        }
        __syncthreads();
    }

#pragma unroll
    for (int i = 0; i < 4; i++) {
        int row = rowBase + ty * 4 + i;
        if (row >= Nrows) continue;
        int col0 = colBase + tx * 4;
        if (col0 >= M) continue;
        float4 v = make_float4(acc[i][0], acc[i][1], acc[i][2], acc[i][3]);
        if (bias) {
            v.x += bias[col0 + 0]; v.y += bias[col0 + 1];
            v.z += bias[col0 + 2]; v.w += bias[col0 + 3];
        }
        if (relu) {
            v.x = fmaxf(v.x, 0.f); v.y = fmaxf(v.y, 0.f);
            v.z = fmaxf(v.z, 0.f); v.w = fmaxf(v.w, 0.f);
        }
        *reinterpret_cast<float4*>(&out[(size_t)row * ldc + col0]) = v;
    }
}

// ---------------------------------------------------------------------------
// Fold attention vectors into input space: u[h,k] = sum_f att[h,f] * W[h*F+f, k]
// ---------------------------------------------------------------------------
template <int HH, int F, int K>
__global__ __launch_bounds__(256) void fold_att(
    const float* __restrict__ W, const float* __restrict__ as_,
    const float* __restrict__ ad_, float* __restrict__ us,
    float* __restrict__ ud, const int* __restrict__ flag)
{
    if (*flag == 0) return;
    const int b   = blockIdx.x;        // 0 .. 2*HH-1
    const int sel = b / HH;
    const int h   = b % HH;
    const float* att = sel ? ad_ : as_;
    float* uo = sel ? ud : us;

    constexpr int NG = 256 / K;
    const int k  = threadIdx.x % K;
    const int fg = threadIdx.x / K;

    float s = 0.f;
#pragma unroll
    for (int f = fg; f < F; f += NG)
        s += att[h * F + f] * W[(size_t)(h * F + f) * K + k];

    __shared__ float red[256];
    red[threadIdx.x] = s;
    __syncthreads();
    if (fg == 0) {
        float tot = s;
#pragma unroll
        for (int g = 1; g < NG; g++) tot += red[g * K + k];
        uo[h * K + k] = tot;
    }
}

// ---------------------------------------------------------------------------
// a_s[n,h] = feat[n,:] . u_s[h,:]  (and a_d).  64/K nodes per wave.
// ---------------------------------------------------------------------------
template <int K, int HH>
__global__ __launch_bounds__(256) void att_from_x(
    const float* __restrict__ xin, const float* __restrict__ us,
    const float* __restrict__ ud, float* __restrict__ as_out,
    float* __restrict__ ad_out, const int* __restrict__ flag)
{
    if (*flag == 0) return;
    constexpr int NPW = WAVE / K;
    const int wid  = threadIdx.x >> 6;
    const int lane = threadIdx.x & 63;
    const int sub  = lane / K;
    const int col  = lane % K;
    const int node = (blockIdx.x * 4 + wid) * NPW + sub;

    float v = 0.f;
    if (node < NODES) v = xin[(size_t)node * K + col];
    float ps[HH], pd[HH];
#pragma unroll
    for (int h = 0; h < HH; h++) {
        ps[h] = v * us[h * K + col];
        pd[h] = v * ud[h * K + col];
    }
#pragma unroll
    for (int off = K / 2; off; off >>= 1) {
#pragma unroll
        for (int h = 0; h < HH; h++) {
            ps[h] += __shfl_xor(ps[h], off);
            pd[h] += __shfl_xor(pd[h], off);
        }
    }
    if (col == 0 && node < NODES) {
#pragma unroll
        for (int h = 0; h < HH; h++) {
            as_out[node * HH + h] = ps[h];
            ad_out[node * HH + h] = pd[h];
        }
    }
}

// ---------------------------------------------------------------------------
// GAT aggregation of bf16 RAW features (layers 1/3) -> bf16 output.
// Fast path (deg <= 64): one edge/lane softmax in regs; gather: 8 bf16/lane,
// wave-uniform trip count (all shfl source lanes active).
// ---------------------------------------------------------------------------
template <int K, int HH>
__global__ __launch_bounds__(256) void gat_aggr_x(
    const unsigned short* __restrict__ xb, const float* __restrict__ as_,
    const float* __restrict__ ad_, const int* __restrict__ rowptr,
    const int* __restrict__ csr_src, unsigned short* __restrict__ aggb,
    const int* __restrict__ flag)
{
    if (*flag == 0) return;
    const int node = blockIdx.x * 4 + (threadIdx.x >> 6);
    const int lane = threadIdx.x & 63;
    if (node >= NODES) return;

    const int beg = rowptr[node], end = rowptr[node + 1];
    const int deg = end - beg;

    float adv[HH];
#pragma unroll
    for (int h = 0; h < HH; h++) adv[h] = ad_[node * HH + h];

    float wl[HH];
    float mx[HH], rden[HH];
    const bool fast = (deg <= WAVE);

    if (fast) {
        float e[HH];
        int i = beg + lane;
        if (i < end) {
            int s = csr_src[i];
#pragma unroll
            for (int h = 0; h < HH; h++)
                e[h] = lrelu(as_[s * HH + h] + adv[h]);
        } else {
#pragma unroll
            for (int h = 0; h < HH; h++) e[h] = -1e30f;
        }
#pragma unroll
        for (int h = 0; h < HH; h++) {
            mx[h] = e[h];
#pragma unroll
            for (int off = 32; off; off >>= 1)
                mx[h] = fmaxf(mx[h], __shfl_xor(mx[h], off));
            float ex = __expf(e[h] - mx[h]);
            wl[h] = ex;
            float dn = ex;
#pragma unroll
            for (int off = 32; off; off >>= 1)
                dn += __shfl_xor(dn, off);
            rden[h] = 1.f / dn;
        }
    } else {
        float den[HH];
#pragma unroll
        for (int h = 0; h < HH; h++) { mx[h] = -1e30f; den[h] = 0.f; }
        for (int i = beg + lane; i < end; i += WAVE) {
            int s = csr_src[i];
#pragma unroll
            for (int h = 0; h < HH; h++)
                mx[h] = fmaxf(mx[h], lrelu(as_[s * HH + h] + adv[h]));
        }
#pragma unroll
        for (int h = 0; h < HH; h++)
#pragma unroll
            for (int off = 32; off; off >>= 1)
                mx[h] = fmaxf(mx[h], __shfl_xor(mx[h], off));
        for (int i = beg + lane; i < end; i += WAVE) {
            int s = csr_src[i];
#pragma unroll
            for (int h = 0; h < HH; h++)
                den[h] += __expf(lrelu(as_[s * HH + h] + adv[h]) - mx[h]);
        }
#pragma unroll
        for (int h = 0; h < HH; h++) {
#pragma unroll
            for (int off = 32; off; off >>= 1)
                den[h] += __shfl_xor(den[h], off);
            rden[h] = 1.f / den[h];
        }
        wl[0] = 0.f;
    }

    constexpr int LPG = K / 8;          // lanes per edge, 8 bf16 (16B) each
    constexpr int GR  = WAVE / LPG;     // edges in flight per iter
    const int esub = lane / LPG;
    const int c8   = lane % LPG;

    float acc[HH][8];
#pragma unroll
    for (int h = 0; h < HH; h++)
#pragma unroll
        for (int j = 0; j < 8; j++) acc[h][j] = 0.f;

    if (fast) {
        const int iters = (deg + GR - 1) / GR;   // wave-uniform
        for (int it = 0; it < iters; ++it) {
            const int i = beg + it * GR + esub;
            const bool valid = (i < end);
            const int srcl = valid ? (i - beg) : 0;
            float w[HH];
#pragma unroll
            for (int h = 0; h < HH; h++)
                w[h] = __shfl(wl[h], srcl);      // all lanes active
            if (valid) {
                int s = csr_src[i];
                uint4 q = *reinterpret_cast<const uint4*>(&xb[(size_t)s * K + c8 * 8]);
                float v[8];
                unpack8(q, v);
#pragma unroll
                for (int h = 0; h < HH; h++)
#pragma unroll
                    for (int j = 0; j < 8; j++)
                        acc[h][j] += v[j] * w[h];
            }
        }
    } else {
        for (int i = beg + esub; i < end; i += GR) {
            int s = csr_src[i];
            float w[HH];
#pragma unroll
            for (int h = 0; h < HH; h++)
                w[h] = __expf(lrelu(as_[s * HH + h] + adv[h]) - mx[h]);
            uint4 q = *reinterpret_cast<const uint4*>(&xb[(size_t)s * K + c8 * 8]);
            float v[8];
            unpack8(q, v);
#pragma unroll
            for (int h = 0; h < HH; h++)
#pragma unroll
                for (int j = 0; j < 8; j++)
                    acc[h][j] += v[j] * w[h];
        }
    }
#pragma unroll
    for (int off = LPG; off < WAVE; off <<= 1)
#pragma unroll
        for (int h = 0; h < HH; h++)
#pragma unroll
            for (int j = 0; j < 8; j++)
                acc[h][j] += __shfl_xor(acc[h][j], off);

    if (esub == 0) {
#pragma unroll
        for (int h = 0; h < HH; h++) {
            float o[8];
#pragma unroll
            for (int j = 0; j < 8; j++) o[j] = acc[h][j] * rden[h];
            *reinterpret_cast<uint4*>(&aggb[(size_t)node * (HH * K) + h * K + c8 * 8]) = pack8(o);
        }
    }
}

// ---------------------------------------------------------------------------
// GAT aggregation of bf16 PROJECTED features (layers 2/4), +bias (+relu).
// fp32 out, optional bf16 shadow copy (for next layer's gather).
// ---------------------------------------------------------------------------
template <int HF, int RELU, int OUTB>
__global__ __launch_bounds__(256) void gat_aggr_h(
    const unsigned short* __restrict__ hb, const float* __restrict__ as_,
    const float* __restrict__ ad_, const int* __restrict__ rowptr,
    const int* __restrict__ csr_src, const float* __restrict__ bias,
    float* __restrict__ out, unsigned short* __restrict__ outb,
    const int* __restrict__ flag)
{
    if (*flag == 0) return;
    const int node = blockIdx.x * 4 + (threadIdx.x >> 6);
    const int lane = threadIdx.x & 63;
    if (node >= NODES) return;

    const int beg = rowptr[node], end = rowptr[node + 1];
    const int deg = end - beg;
    const float adv = ad_[node];

    float wl, mx, rden;
    const bool fast = (deg <= WAVE);

    if (fast) {
        int i = beg + lane;
        float e = -1e30f;
        if (i < end) {
            int s = csr_src[i];
            e = lrelu(as_[s] + adv);
        }
        mx = e;
#pragma unroll
        for (int off = 32; off; off >>= 1)
            mx = fmaxf(mx, __shfl_xor(mx, off));
        wl = __expf(e - mx);
        float dn = wl;
#pragma unroll
        for (int off = 32; off; off >>= 1)
            dn += __shfl_xor(dn, off);
        rden = 1.f / dn;
    } else {
        mx = -1e30f;
        float den = 0.f;
        for (int i = beg + lane; i < end; i += WAVE) {
            int s = csr_src[i];
            mx = fmaxf(mx, lrelu(as_[s] + adv));
        }
#pragma unroll
        for (int off = 32; off; off >>= 1)
            mx = fmaxf(mx, __shfl_xor(mx, off));
        for (int i = beg + lane; i < end; i += WAVE) {
            int s = csr_src[i];
            den += __expf(lrelu(as_[s] + adv) - mx);
        }
#pragma unroll
        for (int off = 32; off; off >>= 1)
            den += __shfl_xor(den, off);
        rden = 1.f / den;
        wl = 0.f;
    }

    constexpr int LPG = HF / 8;
    constexpr int GR  = WAVE / LPG;
    const int esub = lane / LPG;
    const int c8   = lane % LPG;

    float acc[8];
#pragma unroll
    for (int j = 0; j < 8; j++) acc[j] = 0.f;

    if (fast) {
        const int iters = (deg + GR - 1) / GR;   // wave-uniform
        for (int it = 0; it < iters; ++it) {
            const int i = beg + it * GR + esub;
            const bool valid = (i < end);
            const int srcl = valid ? (i - beg) : 0;
            float w = __shfl(wl, srcl);
            if (valid) {
                int s = csr_src[i];
                uint4 q = *reinterpret_cast<const uint4*>(&hb[(size_t)s * HF + c8 * 8]);
                float v[8];
                unpack8(q, v);
#pragma unroll
                for (int j = 0; j < 8; j++) acc[j] += v[j] * w;
            }
        }
    } else {
        for (int i = beg + esub; i < end; i += GR) {
            int s = csr_src[i];
            float w = __expf(lrelu(as_[s] + adv) - mx);
            uint4 q = *reinterpret_cast<const uint4*>(&hb[(size_t)s * HF + c8 * 8]);
            float v[8];
            unpack8(q, v);
#pragma unroll
            for (int j = 0; j < 8; j++) acc[j] += v[j] * w;
        }
    }
#pragma unroll
    for (int off = LPG; off < WAVE; off <<= 1)
#pragma unroll
        for (int j = 0; j < 8; j++)
            acc[j] += __shfl_xor(acc[j], off);

    if (esub == 0) {
        const int col0 = c8 * 8;
        float o[8];
#pragma unroll
        for (int j = 0; j < 8; j++) {
            o[j] = acc[j] * rden + bias[col0 + j];
            if (RELU) o[j] = fmaxf(o[j], 0.f);
        }
        float4 o0 = make_float4(o[0], o[1], o[2], o[3]);
        float4 o1 = make_float4(o[4], o[5], o[6], o[7]);
        *reinterpret_cast<float4*>(&out[(size_t)node * HF + col0]) = o0;
        *reinterpret_cast<float4*>(&out[(size_t)node * HF + col0 + 4]) = o1;
        if (OUTB)
            *reinterpret_cast<uint4*>(&outb[(size_t)node * HF + col0]) = pack8(o);
    }
}

// ---------------------------------------------------------------------------
// CSR build kernels
// ---------------------------------------------------------------------------
__global__ void count_deg(const int* __restrict__ ei, int* __restrict__ deg,
                          int E_, int Nn, const int* __restrict__ flag)
{
    if (*flag == 0) return;
    int e = blockIdx.x * blockDim.x + threadIdx.x;
    int tot = E_ + Nn;
    if (e >= tot) return;
    int dst = (e < E_) ? ei[E_ + e] : (e - E_);
    atomicAdd(&deg[dst], 1);
}

__global__ __launch_bounds__(SCAN_T) void scan_deg(
    const int* __restrict__ deg, int* __restrict__ rowptr,
    int* __restrict__ cursor, const int* __restrict__ flag)
{
    if (*flag == 0) return;
    __shared__ int sums[SCAN_T];
    const int t = threadIdx.x;
    const int base = t * SCAN_CH;

    int v[SCAN_CH];
    const int4* dp = reinterpret_cast<const int4*>(deg + base);
#pragma unroll
    for (int j = 0; j < SCAN_CH / 4; j++) {
        int4 q = dp[j];
        v[4 * j + 0] = q.x; v[4 * j + 1] = q.y;
        v[4 * j + 2] = q.z; v[4 * j + 3] = q.w;
    }
    int s = 0;
#pragma unroll
    for (int j = 0; j < SCAN_CH; j++) s += v[j];
    sums[t] = s;
    __syncthreads();
    for (int off = 1; off < SCAN_T; off <<= 1) {
        int x = (t >= off) ? sums[t - off] : 0;
        __syncthreads();
        sums[t] += x;
        __syncthreads();
    }
    int run = sums[t] - s;
    if (t == 0) rowptr[0] = 0;
#pragma unroll
    for (int j = 0; j < SCAN_CH; j++) {
        cursor[base + j] = run;
        run += v[j];
        rowptr[base + j + 1] = run;
    }
}

__global__ void scatter_edges(const int* __restrict__ ei, int* __restrict__ cursor,
                              int* __restrict__ csr_src, int E_, int Nn,
                              const int* __restrict__ flag)
{
    if (*flag == 0) return;
    int e = blockIdx.x * blockDim.x + threadIdx.x;
    int tot = E_ + Nn;
    if (e >= tot) return;
    int src, dst;
    if (e < E_) { src = ei[e]; dst = ei[E_ + e]; }
    else        { src = e - E_; dst = src; }
    int pos = atomicAdd(&cursor[dst], 1);
    csr_src[pos] = src;
}

// ---------------------------------------------------------------------------
extern "C" void kernel_launch(void* const* d_in, const int* in_sizes, int n_in,
                              void* d_out, int out_size, void* d_ws, size_t ws_size,
                              hipStream_t stream)
{
    const float* x    = (const float*)d_in[0];
    const int*   ei   = (const int*)d_in[1];
    const int*   flag = (const int*)d_in[2];
    const float* W1 = (const float*)d_in[3];
    const float* as1 = (const float*)d_in[4];
    const float* ad1 = (const float*)d_in[5];
    const float* b1 = (const float*)d_in[6];
    const float* W2 = (const float*)d_in[7];
    const float* as2 = (const float*)d_in[8];
    const float* ad2 = (const float*)d_in[9];
    const float* b2 = (const float*)d_in[10];
    const float* W3 = (const float*)d_in[11];
    const float* as3 = (const float*)d_in[12];
    const float* ad3 = (const float*)d_in[13];
    const float* b3 = (const float*)d_in[14];
    const float* W4 = (const float*)d_in[15];
    const float* as4 = (const float*)d_in[16];
    const float* ad4 = (const float*)d_in[17];
    const float* b4 = (const float*)d_in[18];
    const float* el1w = (const float*)d_in[19];
    const float* el1b = (const float*)d_in[20];
    const float* el2w = (const float*)d_in[21];
    const float* el2b = (const float*)d_in[22];
    const float* dl1w = (const float*)d_in[23];
    const float* dl1b = (const float*)d_in[24];
    const float* dl2w = (const float*)d_in[25];
    const float* dl2b = (const float*)d_in[26];

    const int E_   = in_sizes[1] / 2;
    const int Etot = E_ + NODES;

    char* base = (char*)d_ws;
    size_t off = 0;
    auto carve = [&](size_t bytes) -> void* {
        void* p = base + off;
        off = (off + bytes + 255) & ~(size_t)255;
        return p;
    };
    float* T0  = (float*)carve((size_t)NODES * 128 * 4);   // dense intermediate
    float* A   = (float*)carve((size_t)NODES * 256 * 4);   // dense intermediate
    float* Bz  = (float*)carve((size_t)NODES * 32 * 4);    // z (fp32, for L3 dots)
    float* asb = (float*)carve((size_t)NODES * 2 * 4);     // L1/L3 dots
    float* adb = (float*)carve((size_t)NODES * 2 * 4);
    float* as2b = (float*)carve((size_t)NODES * 4);        // L2 dots (atomic)
    float* ad2b = (float*)carve((size_t)NODES * 4);
    float* as4b = (float*)carve((size_t)NODES * 4);        // L4 dots (atomic)
    float* ad4b = (float*)carve((size_t)NODES * 4);
    float* u1s = (float*)carve(2 * 64 * 4);
    float* u1d = (float*)carve(2 * 64 * 4);
    float* u3s = (float*)carve(2 * 32 * 4);
    float* u3d = (float*)carve(2 * 32 * 4);
    unsigned short* xb   = (unsigned short*)carve((size_t)NODES * 64 * 2);   // bf16 x
    unsigned short* aggb = (unsigned short*)carve((size_t)NODES * 128 * 2);  // bf16 agg (L1/L3)
    unsigned short* Ab   = (unsigned short*)carve((size_t)NODES * 256 * 2);  // bf16 L1/L3 out
    unsigned short* T1b  = (unsigned short*)carve((size_t)NODES * 64 * 2);   // bf16 h2/h4
    unsigned short* Bzb  = (unsigned short*)carve((size_t)NODES * 32 * 2);   // bf16 z
    unsigned short* wb1  = (unsigned short*)carve(256 * 64 * 2);
    unsigned short* wb2  = (unsigned short*)carve(32 * 256 * 2);
    unsigned short* wb3  = (unsigned short*)carve(256 * 32 * 2);
    unsigned short* wb4  = (unsigned short*)carve(64 * 256 * 2);
    int* deg    = (int*)carve((size_t)SCAN_CAP * 4);
    int* rowptr = (int*)carve((size_t)(SCAN_CAP + 1) * 4);
    int* cursor = (int*)carve((size_t)SCAN_CAP * 4);
    int* csr    = (int*)carve((size_t)Etot * 4);
    (void)ws_size; (void)n_in; (void)out_size;

    float* outp = (float*)d_out;

    const int nodeBlocks = (NODES + 3) / 4;
    const int edgeBlocks = (Etot + 255) / 256;
    dim3 blk(256);
    const int rowTiles = (NODES + 63) / 64;   // 469

    // ---- prep (zero + cvt) and CSR build ----
    prep<<<2048, 256, 0, stream>>>(deg, as2b, ad2b, as4b, ad4b,
                                   W1, wb1, W2, wb2, W3, wb3, W4, wb4,
                                   x, xb, flag);
    count_deg<<<edgeBlocks, 256, 0, stream>>>(ei, deg, E_, NODES, flag);
    scan_deg<<<1, SCAN_T, 0, stream>>>(deg, rowptr, cursor, flag);
    scatter_edges<<<edgeBlocks, 256, 0, stream>>>(ei, cursor, csr, E_, NODES, flag);

    // ---- Layer 1: GAT(64 -> 128 x 2 heads) + ReLU [aggregate-then-project] ----
    fold_att<2, 128, 64><<<4, 256, 0, stream>>>(W1, as1, ad1, u1s, u1d, flag);
    att_from_x<64, 2><<<nodeBlocks, blk, 0, stream>>>(x, u1s, u1d, asb, adb, flag);
    gat_aggr_x<64, 2><<<nodeBlocks, blk, 0, stream>>>(xb, asb, adb, rowptr, csr, aggb, flag);
    gemm_mfma<64, 128, 1, 1, 0><<<dim3(rowTiles, 8, 2), blk, 0, stream>>>(
        aggb, 128, wb1, b1, Ab, 256, nullptr, nullptr, nullptr, nullptr, flag, NODES);

    // ---- Layer 2: GAT(256 -> 32, 1 head): MFMA gemm (bf16 out) + atomic dots ----
    gemm_mfma<256, 32, 1, 0, 1><<<dim3(rowTiles, 2, 1), blk, 0, stream>>>(
        Ab, 256, wb2, nullptr, T1b, 32, as2, ad2, as2b, ad2b, flag, NODES);
    gat_aggr_h<32, 0, 1><<<nodeBlocks, blk, 0, stream>>>(T1b, as2b, ad2b, rowptr, csr, b2, Bz, Bzb, flag);

    // ---- Layer 3: GAT(32 -> 128 x 2 heads) + ReLU [aggregate-then-project] ----
    fold_att<2, 128, 32><<<4, 256, 0, stream>>>(W3, as3, ad3, u3s, u3d, flag);
    att_from_x<32, 2><<<(NODES + 7) / 8, blk, 0, stream>>>(Bz, u3s, u3d, asb, adb, flag);
    gat_aggr_x<32, 2><<<nodeBlocks, blk, 0, stream>>>(Bzb, asb, adb, rowptr, csr, aggb, flag);
    gemm_mfma<32, 128, 1, 1, 0><<<dim3(rowTiles, 8, 2), blk, 0, stream>>>(
        aggb, 64, wb3, b3, Ab, 256, nullptr, nullptr, nullptr, nullptr, flag, NODES);

    // ---- Layer 4: GAT(256 -> 64, 1 head): MFMA gemm (bf16 out) + atomic dots ----
    gemm_mfma<256, 64, 1, 0, 1><<<dim3(rowTiles, 4, 1), blk, 0, stream>>>(
        Ab, 256, wb4, nullptr, T1b, 64, as4, ad4, as4b, ad4b, flag, NODES);
    gat_aggr_h<64, 0, 0><<<nodeBlocks, blk, 0, stream>>>(T1b, as4b, ad4b, rowptr, csr, b4, outp, nullptr, flag);

    // ---- Dense path (use_neighbors == 0), fp32, unchanged ----
    gemm_xwt<<<dim3(2, rowTiles, 1), blk, 0, stream>>>(x,  64,  el1w, el1b, T0,   128, NODES, 128, 64, 1, flag, 0);
    gemm_xwt<<<dim3(1, rowTiles, 1), blk, 0, stream>>>(T0, 128, el2w, el2b, Bz,   32,  NODES, 32, 128, 0, flag, 0);
    gemm_xwt<<<dim3(2, rowTiles, 1), blk, 0, stream>>>(Bz, 32,  dl1w, dl1b, A,    128, NODES, 128, 32, 1, flag, 0);
    gemm_xwt<<<dim3(1, rowTiles, 1), blk, 0, stream>>>(A,  128, dl2w, dl2b, outp, 64,  NODES, 64, 128, 0, flag, 0);
}

// Round 10
// 382.131 us; speedup vs baseline: 1.0116x; 1.0116x over previous
//
#include <hip/hip_runtime.h>
#include <hip/hip_bf16.h>
#include <math.h>

#define NODES 30000
#define WAVE 64
#define SCAN_T 1024
#define SCAN_CH 32
#define SCAN_CAP (SCAN_T * SCAN_CH)   // 32768 >= NODES, branchless scan

typedef __attribute__((ext_vector_type(8))) short short8b;   // 8 bf16 (4 VGPRs)
typedef __attribute__((ext_vector_type(4))) float floatx4;   // MFMA C/D

static __device__ __forceinline__ float lrelu(float x) {
    return (x > 0.f) ? x : 0.2f * x;
}

// fp32 -> bf16 round-to-nearest-even
static __device__ __forceinline__ unsigned short f2bf(float f) {
    union { float f; unsigned u; } v; v.f = f;
    unsigned r = v.u + 0x7FFF + ((v.u >> 16) & 1);
    return (unsigned short)(r >> 16);
}

// unpack 8 bf16 (uint4) -> 8 floats
static __device__ __forceinline__ void unpack8(uint4 q, float* v) {
    v[0] = __uint_as_float(q.x << 16); v[1] = __uint_as_float(q.x & 0xFFFF0000u);
    v[2] = __uint_as_float(q.y << 16); v[3] = __uint_as_float(q.y & 0xFFFF0000u);
    v[4] = __uint_as_float(q.z << 16); v[5] = __uint_as_float(q.z & 0xFFFF0000u);
    v[6] = __uint_as_float(q.w << 16); v[7] = __uint_as_float(q.w & 0xFFFF0000u);
}

// pack 8 floats -> 8 bf16 (uint4)
static __device__ __forceinline__ uint4 pack8(const float* v) {
    uint4 p;
    p.x = (unsigned)f2bf(v[0]) | ((unsigned)f2bf(v[1]) << 16);
    p.y = (unsigned)f2bf(v[2]) | ((unsigned)f2bf(v[3]) << 16);
    p.z = (unsigned)f2bf(v[4]) | ((unsigned)f2bf(v[5]) << 16);
    p.w = (unsigned)f2bf(v[6]) | ((unsigned)f2bf(v[7]) << 16);
    return p;
}

// ---------------------------------------------------------------------------
// Fused prep (GAT path): zero deg + dots buffers, cvt weights & x to bf16.
// ---------------------------------------------------------------------------
__global__ __launch_bounds__(256) void prep(
    int* __restrict__ deg,
    float* __restrict__ z0, float* __restrict__ z1,
    float* __restrict__ z2, float* __restrict__ z3,
    const float* __restrict__ W1, unsigned short* __restrict__ wb1,
    const float* __restrict__ W2, unsigned short* __restrict__ wb2,
    const float* __restrict__ W3, unsigned short* __restrict__ wb3,
    const float* __restrict__ W4, unsigned short* __restrict__ wb4,
    const float* __restrict__ x, unsigned short* __restrict__ xb,
    const int* __restrict__ flag)
{
    if (*flag == 0) return;
    const int tid = blockIdx.x * blockDim.x + threadIdx.x;
    const int stride = gridDim.x * blockDim.x;
    for (int i = tid; i < SCAN_CAP / 4; i += stride)
        reinterpret_cast<int4*>(deg)[i] = make_int4(0, 0, 0, 0);
    for (int i = tid; i < NODES; i += stride) {
        z0[i] = 0.f; z1[i] = 0.f; z2[i] = 0.f; z3[i] = 0.f;
    }
    for (int i = tid; i < 256 * 64; i += stride) wb1[i] = f2bf(W1[i]);
    for (int i = tid; i < 32 * 256; i += stride) wb2[i] = f2bf(W2[i]);
    for (int i = tid; i < 256 * 32; i += stride) wb3[i] = f2bf(W3[i]);
    for (int i = tid; i < 64 * 256; i += stride) wb4[i] = f2bf(W4[i]);
    for (int i = tid; i < NODES * 64 / 4; i += stride) {
        float4 v = reinterpret_cast<const float4*>(x)[i];
        ushort4 o;
        o.x = f2bf(v.x); o.y = f2bf(v.y); o.z = f2bf(v.z); o.w = f2bf(v.w);
        reinterpret_cast<ushort4*>(xb)[i] = o;
    }
}

// ---------------------------------------------------------------------------
// MFMA GEMM: out[n, z*M + ct*16 + c] = Xb[n, z*K + k] @ Wb[z*M + m, k]^T
// bf16 in, fp32 accumulate. One 16x16 C tile per wave, LDS-free.
// C frag: col = lane&15, row = (lane>>4)*4 + i  (m89-verified).
// Optional fused attention dots (heads==1) via atomics on zeroed buffers.
// ---------------------------------------------------------------------------
template <int K, int M, int OUT_BF16, int RELU, int DOTS>
__global__ __launch_bounds__(256) void gemm_mfma(
    const unsigned short* __restrict__ Xb, int ldx,
    const unsigned short* __restrict__ Wb,
    const float* __restrict__ bias,
    void* __restrict__ outv, int ldc,
    const float* __restrict__ att_s, const float* __restrict__ att_d,
    float* __restrict__ as_out, float* __restrict__ ad_out,
    const int* __restrict__ flag, int Nrows)
{
    if (*flag == 0) return;
    constexpr int KC = K / 32;
    const int w    = threadIdx.x >> 6;
    const int lane = threadIdx.x & 63;
    const int z    = blockIdx.z;
    const int ct   = blockIdx.y;
    const int rowBase = blockIdx.x * 64 + w * 16;

    const int lr = lane & 15;
    const int lk = (lane >> 4) * 8;

    const int arow = min(rowBase + lr, Nrows - 1);
    const unsigned short* ap = Xb + (size_t)arow * ldx + z * K + lk;
    short8b a[KC];
#pragma unroll
    for (int kc = 0; kc < KC; kc++)
        a[kc] = *reinterpret_cast<const short8b*>(ap + kc * 32);

    const unsigned short* bp = Wb + (size_t)(z * M + ct * 16 + lr) * K + lk;
    short8b b[KC];
#pragma unroll
    for (int kc = 0; kc < KC; kc++)
        b[kc] = *reinterpret_cast<const short8b*>(bp + kc * 32);

    floatx4 c = {0.f, 0.f, 0.f, 0.f};
#pragma unroll
    for (int kc = 0; kc < KC; kc++)
        c = __builtin_amdgcn_mfma_f32_16x16x32_bf16(a[kc], b[kc], c, 0, 0, 0);

    const int colg = z * M + ct * 16 + lr;
    const float bv = bias ? bias[colg] : 0.f;

#pragma unroll
    for (int i = 0; i < 4; i++) {
        int r = rowBase + (lane >> 4) * 4 + i;
        float v = c[i] + bv;
        if (RELU) v = fmaxf(v, 0.f);
        if (r < Nrows) {
            if (OUT_BF16)
                ((unsigned short*)outv)[(size_t)r * ldc + colg] = f2bf(v);
            else
                ((float*)outv)[(size_t)r * ldc + colg] = v;
        }
    }

    if (DOTS) {  // partial row-dot over this tile's 16 cols (fp32 c) -> atomic
        const float as_v = att_s[colg];
        const float ad_v = att_d[colg];
#pragma unroll
        for (int i = 0; i < 4; i++) {
            int r = rowBase + (lane >> 4) * 4 + i;
            float ps = c[i] * as_v;
            float pd = c[i] * ad_v;
#pragma unroll
            for (int off = 8; off; off >>= 1) {
                ps += __shfl_xor(ps, off);
                pd += __shfl_xor(pd, off);
            }
            if (lr == 0 && r < Nrows) {
                atomicAdd(&as_out[r], ps);
                atomicAdd(&ad_out[r], pd);
            }
        }
    }
}

// ---------------------------------------------------------------------------
// fp32 GEMM (dense / use_neighbors==0 path only).
// ---------------------------------------------------------------------------
__global__ __launch_bounds__(256) void gemm_xwt(
    const float* __restrict__ X, int lda, const float* __restrict__ W,
    const float* __restrict__ bias, float* __restrict__ out, int ldc,
    int Nrows, int M, int K, int relu,
    const int* __restrict__ flag, int wantFlag)
{
    if (((*flag != 0) ? 1 : 0) != wantFlag) return;

    const int z = blockIdx.z;
    X += (size_t)z * K;
    W += (size_t)z * M * K;
    if (bias) bias += (size_t)z * M;
    out += (size_t)z * M;

    __shared__ float As[16][68];
    __shared__ float Bs[16][68];

    const int t  = threadIdx.x;
    const int tx = t & 15;
    const int ty = t >> 4;
    const int rowBase = blockIdx.y * 64;
    const int colBase = blockIdx.x * 64;

    float acc[4][4];
#pragma unroll
    for (int i = 0; i < 4; i++)
#pragma unroll
        for (int j = 0; j < 4; j++) acc[i][j] = 0.f;

    const int r_ld = t >> 2;
    const int k_ld = (t & 3) * 4;

    for (int kt = 0; kt < K; kt += 16) {
        float4 av = make_float4(0.f, 0.f, 0.f, 0.f);
        int grow = rowBase + r_ld;
        if (grow < Nrows)
            av = *reinterpret_cast<const float4*>(&X[(size_t)grow * lda + kt + k_ld]);
        As[k_ld + 0][r_ld] = av.x;
        As[k_ld + 1][r_ld] = av.y;
        As[k_ld + 2][r_ld] = av.z;
        As[k_ld + 3][r_ld] = av.w;
        float4 bv = make_float4(0.f, 0.f, 0.f, 0.f);
        int gm = colBase + r_ld;
        if (gm < M)
            bv = *reinterpret_cast<const float4*>(&W[(size_t)gm * K + kt + k_ld]);
        Bs[k_ld + 0][r_ld] = bv.x;
        Bs[k_ld + 1][r_ld] = bv.y;
        Bs[k_ld + 2][r_ld] = bv.z;
        Bs[k_ld + 3][r_ld] = bv.w;
        __syncthreads();

#pragma unroll
        for (int kk = 0; kk < 16; ++kk) {
            const float4 a = *reinterpret_cast<const float4*>(&As[kk][ty * 4]);
            const float4 b = *reinterpret_cast<const float4*>(&Bs[kk][tx * 4]);
            acc[0][0] += a.x * b.x; acc[0][1] += a.x * b.y; acc[0][2] += a.x * b.z; acc[0][3] += a.x * b.w;
            acc[1][0] += a.y * b.x; acc[1][1] += a.y * b.y; acc[1][2] += a.y * b.z; acc[1][3] += a.y * b.w;
            acc[2][0] += a.z * b.x; acc[2][1] += a.z * b.y; acc[2][2] += a.z * b.z; acc[2][3] += a.z * b.w;
            acc[3][0] += a.w * b.x; acc[3][1] += a.w * b.y; acc[3][2] += a.w * b.z; acc[3][3] += a.w * b.w;
        }
        __syncthreads();
    }

#pragma unroll
    for (int i = 0; i < 4; i++) {
        int row = rowBase + ty * 4 + i;
        if (row >= Nrows) continue;
        int col0 = colBase + tx * 4;
        if (col0 >= M) continue;
        float4 v = make_float4(acc[i][0], acc[i][1], acc[i][2], acc[i][3]);
        if (bias) {
            v.x += bias[col0 + 0]; v.y += bias[col0 + 1];
            v.z += bias[col0 + 2]; v.w += bias[col0 + 3];
        }
        if (relu) {
            v.x = fmaxf(v.x, 0.f); v.y = fmaxf(v.y, 0.f);
            v.z = fmaxf(v.z, 0.f); v.w = fmaxf(v.w, 0.f);
        }
        *reinterpret_cast<float4*>(&out[(size_t)row * ldc + col0]) = v;
    }
}

// ---------------------------------------------------------------------------
// Fold attention vectors into input space (both L1 and L3 in ONE launch):
// u[h,k] = sum_f att[h,f] * W[h*F+f, k].  Blocks 0-3: L1 (K=64), 4-7: L3 (K=32).
// ---------------------------------------------------------------------------
template <int HH, int F, int K>
static __device__ void fold_body(
    const float* __restrict__ W, const float* __restrict__ as_,
    const float* __restrict__ ad_, float* __restrict__ us,
    float* __restrict__ ud, int b)
{
    const int sel = b / HH;
    const int h   = b % HH;
    const float* att = sel ? ad_ : as_;
    float* uo = sel ? ud : us;

    constexpr int NG = 256 / K;
    const int k  = threadIdx.x % K;
    const int fg = threadIdx.x / K;

    float s = 0.f;
#pragma unroll
    for (int f = fg; f < F; f += NG)
        s += att[h * F + f] * W[(size_t)(h * F + f) * K + k];

    __shared__ float red[256];
    red[threadIdx.x] = s;
    __syncthreads();
    if (fg == 0) {
        float tot = s;
#pragma unroll
        for (int g = 1; g < NG; g++) tot += red[g * K + k];
        uo[h * K + k] = tot;
    }
}

__global__ __launch_bounds__(256) void fold_att2(
    const float* __restrict__ W1, const float* __restrict__ as1,
    const float* __restrict__ ad1, float* __restrict__ u1s, float* __restrict__ u1d,
    const float* __restrict__ W3, const float* __restrict__ as3,
    const float* __restrict__ ad3, float* __restrict__ u3s, float* __restrict__ u3d,
    const int* __restrict__ flag)
{
    if (*flag == 0) return;
    const int b = blockIdx.x;   // 0..7
    if (b < 4) fold_body<2, 128, 64>(W1, as1, ad1, u1s, u1d, b);
    else       fold_body<2, 128, 32>(W3, as3, ad3, u3s, u3d, b - 4);
}

// ---------------------------------------------------------------------------
// a_s[n,h] = feat[n,:] . u_s[h,:]  (and a_d).  64/K nodes per wave.
// ---------------------------------------------------------------------------
template <int K, int HH>
__global__ __launch_bounds__(256) void att_from_x(
    const float* __restrict__ xin, const float* __restrict__ us,
    const float* __restrict__ ud, float* __restrict__ as_out,
    float* __restrict__ ad_out, const int* __restrict__ flag)
{
    if (*flag == 0) return;
    constexpr int NPW = WAVE / K;
    const int wid  = threadIdx.x >> 6;
    const int lane = threadIdx.x & 63;
    const int sub  = lane / K;
    const int col  = lane % K;
    const int node = (blockIdx.x * 4 + wid) * NPW + sub;

    float v = 0.f;
    if (node < NODES) v = xin[(size_t)node * K + col];
    float ps[HH], pd[HH];
#pragma unroll
    for (int h = 0; h < HH; h++) {
        ps[h] = v * us[h * K + col];
        pd[h] = v * ud[h * K + col];
    }
#pragma unroll
    for (int off = K / 2; off; off >>= 1) {
#pragma unroll
        for (int h = 0; h < HH; h++) {
            ps[h] += __shfl_xor(ps[h], off);
            pd[h] += __shfl_xor(pd[h], off);
        }
    }
    if (col == 0 && node < NODES) {
#pragma unroll
        for (int h = 0; h < HH; h++) {
            as_out[node * HH + h] = ps[h];
            ad_out[node * HH + h] = pd[h];
        }
    }
}

// ---------------------------------------------------------------------------
// GAT aggregation of bf16 RAW features (layers 1/3) -> bf16 output.
// Fast path (deg <= 64): one edge/lane; BOTH the softmax weight AND the
// source index are kept in lane registers and fetched via __shfl in the
// gather loop — the only memory op on the critical path is the feature load.
// Gather loop is wave-uniform (all shfl source lanes active).
// ---------------------------------------------------------------------------
template <int K, int HH>
__global__ __launch_bounds__(256) void gat_aggr_x(
    const unsigned short* __restrict__ xb, const float* __restrict__ as_,
    const float* __restrict__ ad_, const int* __restrict__ rowptr,
    const int* __restrict__ csr_src, unsigned short* __restrict__ aggb,
    const int* __restrict__ flag)
{
    if (*flag == 0) return;
    const int node = blockIdx.x * 4 + (threadIdx.x >> 6);
    const int lane = threadIdx.x & 63;
    if (node >= NODES) return;

    const int beg = rowptr[node], end = rowptr[node + 1];
    const int deg = end - beg;

    float adv[HH];
#pragma unroll
    for (int h = 0; h < HH; h++) adv[h] = ad_[node * HH + h];

    float wl[HH];
    float mx[HH], rden[HH];
    int s_l = 0;                      // fast path: this lane's edge source
    const bool fast = (deg <= WAVE);

    if (fast) {
        float e[HH];
        int i = beg + lane;
        if (i < end) {
            s_l = csr_src[i];
#pragma unroll
            for (int h = 0; h < HH; h++)
                e[h] = lrelu(as_[s_l * HH + h] + adv[h]);
        } else {
#pragma unroll
            for (int h = 0; h < HH; h++) e[h] = -1e30f;
        }
#pragma unroll
        for (int h = 0; h < HH; h++) {
            mx[h] = e[h];
#pragma unroll
            for (int off = 32; off; off >>= 1)
                mx[h] = fmaxf(mx[h], __shfl_xor(mx[h], off));
            float ex = __expf(e[h] - mx[h]);
            wl[h] = ex;
            float dn = ex;
#pragma unroll
            for (int off = 32; off; off >>= 1)
                dn += __shfl_xor(dn, off);
            rden[h] = 1.f / dn;
        }
    } else {
        float den[HH];
#pragma unroll
        for (int h = 0; h < HH; h++) { mx[h] = -1e30f; den[h] = 0.f; }
        for (int i = beg + lane; i < end; i += WAVE) {
            int s = csr_src[i];
#pragma unroll
            for (int h = 0; h < HH; h++)
                mx[h] = fmaxf(mx[h], lrelu(as_[s * HH + h] + adv[h]));
        }
#pragma unroll
        for (int h = 0; h < HH; h++)
#pragma unroll
            for (int off = 32; off; off >>= 1)
                mx[h] = fmaxf(mx[h], __shfl_xor(mx[h], off));
        for (int i = beg + lane; i < end; i += WAVE) {
            int s = csr_src[i];
#pragma unroll
            for (int h = 0; h < HH; h++)
                den[h] += __expf(lrelu(as_[s * HH + h] + adv[h]) - mx[h]);
        }
#pragma unroll
        for (int h = 0; h < HH; h++) {
#pragma unroll
            for (int off = 32; off; off >>= 1)
                den[h] += __shfl_xor(den[h], off);
            rden[h] = 1.f / den[h];
        }
    }

    constexpr int LPG = K / 8;          // lanes per edge, 8 bf16 (16B) each
    constexpr int GR  = WAVE / LPG;     // edges in flight per iter
    const int esub = lane / LPG;
    const int c8   = lane % LPG;

    float acc[HH][8];
#pragma unroll
    for (int h = 0; h < HH; h++)
#pragma unroll
        for (int j = 0; j < 8; j++) acc[h][j] = 0.f;

    if (fast) {
        const int iters = (deg + GR - 1) / GR;   // wave-uniform
        for (int it = 0; it < iters; ++it) {
            const int i = beg + it * GR + esub;
            const bool valid = (i < end);
            const int srcl = valid ? (i - beg) : 0;
            int s = __shfl(s_l, srcl);           // index from register, no load
            float w[HH];
#pragma unroll
            for (int h = 0; h < HH; h++)
                w[h] = __shfl(wl[h], srcl);      // all lanes active
            if (valid) {
                uint4 q = *reinterpret_cast<const uint4*>(&xb[(size_t)s * K + c8 * 8]);
                float v[8];
                unpack8(q, v);
#pragma unroll
                for (int h = 0; h < HH; h++)
#pragma unroll
                    for (int j = 0; j < 8; j++)
                        acc[h][j] += v[j] * w[h];
            }
        }
    } else {
        for (int i = beg + esub; i < end; i += GR) {
            int s = csr_src[i];
            float w[HH];
#pragma unroll
            for (int h = 0; h < HH; h++)
                w[h] = __expf(lrelu(as_[s * HH + h] + adv[h]) - mx[h]);
            uint4 q = *reinterpret_cast<const uint4*>(&xb[(size_t)s * K + c8 * 8]);
            float v[8];
            unpack8(q, v);
#pragma unroll
            for (int h = 0; h < HH; h++)
#pragma unroll
                for (int j = 0; j < 8; j++)
                    acc[h][j] += v[j] * w[h];
        }
    }
#pragma unroll
    for (int off = LPG; off < WAVE; off <<= 1)
#pragma unroll
        for (int h = 0; h < HH; h++)
#pragma unroll
            for (int j = 0; j < 8; j++)
                acc[h][j] += __shfl_xor(acc[h][j], off);

    if (esub == 0) {
#pragma unroll
        for (int h = 0; h < HH; h++) {
            float o[8];
#pragma unroll
            for (int j = 0; j < 8; j++) o[j] = acc[h][j] * rden[h];
            *reinterpret_cast<uint4*>(&aggb[(size_t)node * (HH * K) + h * K + c8 * 8]) = pack8(o);
        }
    }
}

// ---------------------------------------------------------------------------
// GAT aggregation of bf16 PROJECTED features (layers 2/4), +bias (+relu).
// fp32 out, optional bf16 shadow copy. Same shfl-index fast path.
// ---------------------------------------------------------------------------
template <int HF, int RELU, int OUTB>
__global__ __launch_bounds__(256) void gat_aggr_h(
    const unsigned short* __restrict__ hb, const float* __restrict__ as_,
    const float* __restrict__ ad_, const int* __restrict__ rowptr,
    const int* __restrict__ csr_src, const float* __restrict__ bias,
    float* __restrict__ out, unsigned short* __restrict__ outb,
    const int* __restrict__ flag)
{
    if (*flag == 0) return;
    const int node = blockIdx.x * 4 + (threadIdx.x >> 6);
    const int lane = threadIdx.x & 63;
    if (node >= NODES) return;

    const int beg = rowptr[node], end = rowptr[node + 1];
    const int deg = end - beg;
    const float adv = ad_[node];

    float wl, mx, rden;
    int s_l = 0;
    const bool fast = (deg <= WAVE);

    if (fast) {
        int i = beg + lane;
        float e = -1e30f;
        if (i < end) {
            s_l = csr_src[i];
            e = lrelu(as_[s_l] + adv);
        }
        mx = e;
#pragma unroll
        for (int off = 32; off; off >>= 1)
            mx = fmaxf(mx, __shfl_xor(mx, off));
        wl = __expf(e - mx);
        float dn = wl;
#pragma unroll
        for (int off = 32; off; off >>= 1)
            dn += __shfl_xor(dn, off);
        rden = 1.f / dn;
    } else {
        mx = -1e30f;
        float den = 0.f;
        for (int i = beg + lane; i < end; i += WAVE) {
            int s = csr_src[i];
            mx = fmaxf(mx, lrelu(as_[s] + adv));
        }
#pragma unroll
        for (int off = 32; off; off >>= 1)
            mx = fmaxf(mx, __shfl_xor(mx, off));
        for (int i = beg + lane; i < end; i += WAVE) {
            int s = csr_src[i];
            den += __expf(lrelu(as_[s] + adv) - mx);
        }
#pragma unroll
        for (int off = 32; off; off >>= 1)
            den += __shfl_xor(den, off);
        rden = 1.f / den;
        wl = 0.f;
    }

    constexpr int LPG = HF / 8;
    constexpr int GR  = WAVE / LPG;
    const int esub = lane / LPG;
    const int c8   = lane % LPG;

    float acc[8];
#pragma unroll
    for (int j = 0; j < 8; j++) acc[j] = 0.f;

    if (fast) {
        const int iters = (deg + GR - 1) / GR;   // wave-uniform
        for (int it = 0; it < iters; ++it) {
            const int i = beg + it * GR + esub;
            const bool valid = (i < end);
            const int srcl = valid ? (i - beg) : 0;
            int s = __shfl(s_l, srcl);           // index from register, no load
            float w = __shfl(wl, srcl);
            if (valid) {
                uint4 q = *reinterpret_cast<const uint4*>(&hb[(size_t)s * HF + c8 * 8]);
                float v[8];
                unpack8(q, v);
#pragma unroll
                for (int j = 0; j < 8; j++) acc[j] += v[j] * w;
            }
        }
    } else {
        for (int i = beg + esub; i < end; i += GR) {
            int s = csr_src[i];
            float w = __expf(lrelu(as_[s] + adv) - mx);
            uint4 q = *reinterpret_cast<const uint4*>(&hb[(size_t)s * HF + c8 * 8]);
            float v[8];
            unpack8(q, v);
#pragma unroll
            for (int j = 0; j < 8; j++) acc[j] += v[j] * w;
        }
    }
#pragma unroll
    for (int off = LPG; off < WAVE; off <<= 1)
#pragma unroll
        for (int j = 0; j < 8; j++)
            acc[j] += __shfl_xor(acc[j], off);

    if (esub == 0) {
        const int col0 = c8 * 8;
        float o[8];
#pragma unroll
        for (int j = 0; j < 8; j++) {
            o[j] = acc[j] * rden + bias[col0 + j];
            if (RELU) o[j] = fmaxf(o[j], 0.f);
        }
        float4 o0 = make_float4(o[0], o[1], o[2], o[3]);
        float4 o1 = make_float4(o[4], o[5], o[6], o[7]);
        *reinterpret_cast<float4*>(&out[(size_t)node * HF + col0]) = o0;
        *reinterpret_cast<float4*>(&out[(size_t)node * HF + col0 + 4]) = o1;
        if (OUTB)
            *reinterpret_cast<uint4*>(&outb[(size_t)node * HF + col0]) = pack8(o);
    }
}

// ---------------------------------------------------------------------------
// CSR build kernels
// ---------------------------------------------------------------------------
__global__ void count_deg(const int* __restrict__ ei, int* __restrict__ deg,
                          int E_, int Nn, const int* __restrict__ flag)
{
    if (*flag == 0) return;
    int e = blockIdx.x * blockDim.x + threadIdx.x;
    int tot = E_ + Nn;
    if (e >= tot) return;
    int dst = (e < E_) ? ei[E_ + e] : (e - E_);
    atomicAdd(&deg[dst], 1);
}

__global__ __launch_bounds__(SCAN_T) void scan_deg(
    const int* __restrict__ deg, int* __restrict__ rowptr,
    int* __restrict__ cursor, const int* __restrict__ flag)
{
    if (*flag == 0) return;
    __shared__ int sums[SCAN_T];
    const int t = threadIdx.x;
    const int base = t * SCAN_CH;

    int v[SCAN_CH];
    const int4* dp = reinterpret_cast<const int4*>(deg + base);
#pragma unroll
    for (int j = 0; j < SCAN_CH / 4; j++) {
        int4 q = dp[j];
        v[4 * j + 0] = q.x; v[4 * j + 1] = q.y;
        v[4 * j + 2] = q.z; v[4 * j + 3] = q.w;
    }
    int s = 0;
#pragma unroll
    for (int j = 0; j < SCAN_CH; j++) s += v[j];
    sums[t] = s;
    __syncthreads();
    for (int off = 1; off < SCAN_T; off <<= 1) {
        int x = (t >= off) ? sums[t - off] : 0;
        __syncthreads();
        sums[t] += x;
        __syncthreads();
    }
    int run = sums[t] - s;
    if (t == 0) rowptr[0] = 0;
#pragma unroll
    for (int j = 0; j < SCAN_CH; j++) {
        cursor[base + j] = run;
        run += v[j];
        rowptr[base + j + 1] = run;
    }
}

__global__ void scatter_edges(const int* __restrict__ ei, int* __restrict__ cursor,
                              int* __restrict__ csr_src, int E_, int Nn,
                              const int* __restrict__ flag)
{
    if (*flag == 0) return;
    int e = blockIdx.x * blockDim.x + threadIdx.x;
    int tot = E_ + Nn;
    if (e >= tot) return;
    int src, dst;
    if (e < E_) { src = ei[e]; dst = ei[E_ + e]; }
    else        { src = e - E_; dst = src; }
    int pos = atomicAdd(&cursor[dst], 1);
    csr_src[pos] = src;
}

// ---------------------------------------------------------------------------
extern "C" void kernel_launch(void* const* d_in, const int* in_sizes, int n_in,
                              void* d_out, int out_size, void* d_ws, size_t ws_size,
                              hipStream_t stream)
{
    const float* x    = (const float*)d_in[0];
    const int*   ei   = (const int*)d_in[1];
    const int*   flag = (const int*)d_in[2];
    const float* W1 = (const float*)d_in[3];
    const float* as1 = (const float*)d_in[4];
    const float* ad1 = (const float*)d_in[5];
    const float* b1 = (const float*)d_in[6];
    const float* W2 = (const float*)d_in[7];
    const float* as2 = (const float*)d_in[8];
    const float* ad2 = (const float*)d_in[9];
    const float* b2 = (const float*)d_in[10];
    const float* W3 = (const float*)d_in[11];
    const float* as3 = (const float*)d_in[12];
    const float* ad3 = (const float*)d_in[13];
    const float* b3 = (const float*)d_in[14];
    const float* W4 = (const float*)d_in[15];
    const float* as4 = (const float*)d_in[16];
    const float* ad4 = (const float*)d_in[17];
    const float* b4 = (const float*)d_in[18];
    const float* el1w = (const float*)d_in[19];
    const float* el1b = (const float*)d_in[20];
    const float* el2w = (const float*)d_in[21];
    const float* el2b = (const float*)d_in[22];
    const float* dl1w = (const float*)d_in[23];
    const float* dl1b = (const float*)d_in[24];
    const float* dl2w = (const float*)d_in[25];
    const float* dl2b = (const float*)d_in[26];

    const int E_   = in_sizes[1] / 2;
    const int Etot = E_ + NODES;

    char* base = (char*)d_ws;
    size_t off = 0;
    auto carve = [&](size_t bytes) -> void* {
        void* p = base + off;
        off = (off + bytes + 255) & ~(size_t)255;
        return p;
    };
    float* T0  = (float*)carve((size_t)NODES * 128 * 4);   // dense intermediate
    float* A   = (float*)carve((size_t)NODES * 256 * 4);   // dense intermediate
    float* Bz  = (float*)carve((size_t)NODES * 32 * 4);    // z (fp32, for L3 dots)
    float* asb = (float*)carve((size_t)NODES * 2 * 4);     // L1/L3 dots
    float* adb = (float*)carve((size_t)NODES * 2 * 4);
    float* as2b = (float*)carve((size_t)NODES * 4);        // L2 dots (atomic)
    float* ad2b = (float*)carve((size_t)NODES * 4);
    float* as4b = (float*)carve((size_t)NODES * 4);        // L4 dots (atomic)
    float* ad4b = (float*)carve((size_t)NODES * 4);
    float* u1s = (float*)carve(2 * 64 * 4);
    float* u1d = (float*)carve(2 * 64 * 4);
    float* u3s = (float*)carve(2 * 32 * 4);
    float* u3d = (float*)carve(2 * 32 * 4);
    unsigned short* xb   = (unsigned short*)carve((size_t)NODES * 64 * 2);   // bf16 x
    unsigned short* aggb = (unsigned short*)carve((size_t)NODES * 128 * 2);  // bf16 agg (L1/L3)
    unsigned short* Ab   = (unsigned short*)carve((size_t)NODES * 256 * 2);  // bf16 L1/L3 out
    unsigned short* T1b  = (unsigned short*)carve((size_t)NODES * 64 * 2);   // bf16 h2/h4
    unsigned short* Bzb  = (unsigned short*)carve((size_t)NODES * 32 * 2);   // bf16 z
    unsigned short* wb1  = (unsigned short*)carve(256 * 64 * 2);
    unsigned short* wb2  = (unsigned short*)carve(32 * 256 * 2);
    unsigned short* wb3  = (unsigned short*)carve(256 * 32 * 2);
    unsigned short* wb4  = (unsigned short*)carve(64 * 256 * 2);
    int* deg    = (int*)carve((size_t)SCAN_CAP * 4);
    int* rowptr = (int*)carve((size_t)(SCAN_CAP + 1) * 4);
    int* cursor = (int*)carve((size_t)SCAN_CAP * 4);
    int* csr    = (int*)carve((size_t)Etot * 4);
    (void)ws_size; (void)n_in; (void)out_size;

    float* outp = (float*)d_out;

    const int nodeBlocks = (NODES + 3) / 4;
    const int edgeBlocks = (Etot + 255) / 256;
    dim3 blk(256);
    const int rowTiles = (NODES + 63) / 64;   // 469

    // ---- prep (zero + cvt) and CSR build ----
    prep<<<2048, 256, 0, stream>>>(deg, as2b, ad2b, as4b, ad4b,
                                   W1, wb1, W2, wb2, W3, wb3, W4, wb4,
                                   x, xb, flag);
    count_deg<<<edgeBlocks, 256, 0, stream>>>(ei, deg, E_, NODES, flag);
    scan_deg<<<1, SCAN_T, 0, stream>>>(deg, rowptr, cursor, flag);
    scatter_edges<<<edgeBlocks, 256, 0, stream>>>(ei, cursor, csr, E_, NODES, flag);

    // ---- fold L1+L3 attention vectors (one launch) ----
    fold_att2<<<8, 256, 0, stream>>>(W1, as1, ad1, u1s, u1d,
                                     W3, as3, ad3, u3s, u3d, flag);

    // ---- Layer 1: GAT(64 -> 128 x 2 heads) + ReLU [aggregate-then-project] ----
    att_from_x<64, 2><<<nodeBlocks, blk, 0, stream>>>(x, u1s, u1d, asb, adb, flag);
    gat_aggr_x<64, 2><<<nodeBlocks, blk, 0, stream>>>(xb, asb, adb, rowptr, csr, aggb, flag);
    gemm_mfma<64, 128, 1, 1, 0><<<dim3(rowTiles, 8, 2), blk, 0, stream>>>(
        aggb, 128, wb1, b1, Ab, 256, nullptr, nullptr, nullptr, nullptr, flag, NODES);

    // ---- Layer 2: GAT(256 -> 32, 1 head): MFMA gemm (bf16 out) + atomic dots ----
    gemm_mfma<256, 32, 1, 0, 1><<<dim3(rowTiles, 2, 1), blk, 0, stream>>>(
        Ab, 256, wb2, nullptr, T1b, 32, as2, ad2, as2b, ad2b, flag, NODES);
    gat_aggr_h<32, 0, 1><<<nodeBlocks, blk, 0, stream>>>(T1b, as2b, ad2b, rowptr, csr, b2, Bz, Bzb, flag);

    // ---- Layer 3: GAT(32 -> 128 x 2 heads) + ReLU [aggregate-then-project] ----
    att_from_x<32, 2><<<(NODES + 7) / 8, blk, 0, stream>>>(Bz, u3s, u3d, asb, adb, flag);
    gat_aggr_x<32, 2><<<nodeBlocks, blk, 0, stream>>>(Bzb, asb, adb, rowptr, csr, aggb, flag);
    gemm_mfma<32, 128, 1, 1, 0><<<dim3(rowTiles, 8, 2), blk, 0, stream>>>(
        aggb, 64, wb3, b3, Ab, 256, nullptr, nullptr, nullptr, nullptr, flag, NODES);

    // ---- Layer 4: GAT(256 -> 64, 1 head): MFMA gemm (bf16 out) + atomic dots ----
    gemm_mfma<256, 64, 1, 0, 1><<<dim3(rowTiles, 4, 1), blk, 0, stream>>>(
        Ab, 256, wb4, nullptr, T1b, 64, as4, ad4, as4b, ad4b, flag, NODES);
    gat_aggr_h<64, 0, 0><<<nodeBlocks, blk, 0, stream>>>(T1b, as4b, ad4b, rowptr, csr, b4, outp, nullptr, flag);

    // ---- Dense path (use_neighbors == 0), fp32, unchanged ----
    gemm_xwt<<<dim3(2, rowTiles, 1), blk, 0, stream>>>(x,  64,  el1w, el1b, T0,   128, NODES, 128, 64, 1, flag, 0);
    gemm_xwt<<<dim3(1, rowTiles, 1), blk, 0, stream>>>(T0, 128, el2w, el2b, Bz,   32,  NODES, 32, 128, 0, flag, 0);
    gemm_xwt<<<dim3(2, rowTiles, 1), blk, 0, stream>>>(Bz, 32,  dl1w, dl1b, A,    128, NODES, 128, 32, 1, flag, 0);
    gemm_xwt<<<dim3(1, rowTiles, 1), blk, 0, stream>>>(A,  128, dl2w, dl2b, outp, 64,  NODES, 64, 128, 0, flag, 0);
}

// Round 11
// 370.969 us; speedup vs baseline: 1.0421x; 1.0301x over previous
//
#include <hip/hip_runtime.h>
#include <hip/hip_bf16.h>
#include <math.h>

#define NODES 30000
#define WAVE 64
#define SCAN_T 1024
#define SCAN_CH 32
#define SCAN_CAP (SCAN_T * SCAN_CH)   // 32768 >= NODES, branchless scan

typedef __attribute__((ext_vector_type(8))) short short8b;   // 8 bf16 (4 VGPRs)
typedef __attribute__((ext_vector_type(4))) float floatx4;   // MFMA C/D

static __device__ __forceinline__ float lrelu(float x) {
    return (x > 0.f) ? x : 0.2f * x;
}

// fp32 -> bf16 round-to-nearest-even
static __device__ __forceinline__ unsigned short f2bf(float f) {
    union { float f; unsigned u; } v; v.f = f;
    unsigned r = v.u + 0x7FFF + ((v.u >> 16) & 1);
    return (unsigned short)(r >> 16);
}

// unpack 8 bf16 (uint4) -> 8 floats
static __device__ __forceinline__ void unpack8(uint4 q, float* v) {
    v[0] = __uint_as_float(q.x << 16); v[1] = __uint_as_float(q.x & 0xFFFF0000u);
    v[2] = __uint_as_float(q.y << 16); v[3] = __uint_as_float(q.y & 0xFFFF0000u);
    v[4] = __uint_as_float(q.z << 16); v[5] = __uint_as_float(q.z & 0xFFFF0000u);
    v[6] = __uint_as_float(q.w << 16); v[7] = __uint_as_float(q.w & 0xFFFF0000u);
}

// pack 8 floats -> 8 bf16 (uint4)
static __device__ __forceinline__ uint4 pack8(const float* v) {
    uint4 p;
    p.x = (unsigned)f2bf(v[0]) | ((unsigned)f2bf(v[1]) << 16);
    p.y = (unsigned)f2bf(v[2]) | ((unsigned)f2bf(v[3]) << 16);
    p.z = (unsigned)f2bf(v[4]) | ((unsigned)f2bf(v[5]) << 16);
    p.w = (unsigned)f2bf(v[6]) | ((unsigned)f2bf(v[7]) << 16);
    return p;
}

// ---------------------------------------------------------------------------
// fold body: u[h,k] = sum_f att[h,f] * W[h*F+f, k]  (one block per (sel,h))
// ---------------------------------------------------------------------------
template <int HH, int F, int K>
static __device__ void fold_body(
    const float* __restrict__ W, const float* __restrict__ as_,
    const float* __restrict__ ad_, float* __restrict__ us,
    float* __restrict__ ud, int b, float* red)
{
    const int sel = b / HH;
    const int h   = b % HH;
    const float* att = sel ? ad_ : as_;
    float* uo = sel ? ud : us;

    constexpr int NG = 256 / K;
    const int k  = threadIdx.x % K;
    const int fg = threadIdx.x / K;

    float s = 0.f;
#pragma unroll
    for (int f = fg; f < F; f += NG)
        s += att[h * F + f] * W[(size_t)(h * F + f) * K + k];

    red[threadIdx.x] = s;
    __syncthreads();
    if (fg == 0) {
        float tot = s;
#pragma unroll
        for (int g = 1; g < NG; g++) tot += red[g * K + k];
        uo[h * K + k] = tot;
    }
}

// ---------------------------------------------------------------------------
// Fused prep (GAT path): count_deg atomics (deg pre-zeroed via memset),
// zero dots buffers, cvt weights & x to bf16, fold L1/L3 att vectors
// (blocks 0-7 extra duty).
// ---------------------------------------------------------------------------
__global__ __launch_bounds__(256) void prep2(
    const int* __restrict__ ei, int E_, int* __restrict__ deg,
    float* __restrict__ z0, float* __restrict__ z1,
    float* __restrict__ z2, float* __restrict__ z3,
    const float* __restrict__ W1, unsigned short* __restrict__ wb1,
    const float* __restrict__ W2, unsigned short* __restrict__ wb2,
    const float* __restrict__ W3, unsigned short* __restrict__ wb3,
    const float* __restrict__ W4, unsigned short* __restrict__ wb4,
    const float* __restrict__ x, unsigned short* __restrict__ xb,
    const float* __restrict__ as1, const float* __restrict__ ad1,
    float* __restrict__ u1s, float* __restrict__ u1d,
    const float* __restrict__ as3, const float* __restrict__ ad3,
    float* __restrict__ u3s, float* __restrict__ u3d,
    const int* __restrict__ flag)
{
    if (*flag == 0) return;
    __shared__ float red[256];
    const int tid = blockIdx.x * blockDim.x + threadIdx.x;
    const int stride = gridDim.x * blockDim.x;

    // degree count (deg zeroed by preceding memset)
    const int tot = E_ + NODES;
    for (int e = tid; e < tot; e += stride) {
        int dst = (e < E_) ? ei[E_ + e] : (e - E_);
        atomicAdd(&deg[dst], 1);
    }
    for (int i = tid; i < NODES; i += stride) {
        z0[i] = 0.f; z1[i] = 0.f; z2[i] = 0.f; z3[i] = 0.f;
    }
    for (int i = tid; i < 256 * 64; i += stride) wb1[i] = f2bf(W1[i]);
    for (int i = tid; i < 32 * 256; i += stride) wb2[i] = f2bf(W2[i]);
    for (int i = tid; i < 256 * 32; i += stride) wb3[i] = f2bf(W3[i]);
    for (int i = tid; i < 64 * 256; i += stride) wb4[i] = f2bf(W4[i]);
    for (int i = tid; i < NODES * 64 / 4; i += stride) {
        float4 v = reinterpret_cast<const float4*>(x)[i];
        ushort4 o;
        o.x = f2bf(v.x); o.y = f2bf(v.y); o.z = f2bf(v.z); o.w = f2bf(v.w);
        reinterpret_cast<ushort4*>(xb)[i] = o;
    }

    // fold duty: blocks 0-3 = L1 (K=64), blocks 4-7 = L3 (K=32)
    if (blockIdx.x < 8) {
        __syncthreads();
        if (blockIdx.x < 4)
            fold_body<2, 128, 64>(W1, as1, ad1, u1s, u1d, blockIdx.x, red);
        else
            fold_body<2, 128, 32>(W3, as3, ad3, u3s, u3d, blockIdx.x - 4, red);
    }
}

// ---------------------------------------------------------------------------
// Branchless single-block scan over SCAN_CAP. Writes rowptr and cursor.
// ---------------------------------------------------------------------------
__global__ __launch_bounds__(SCAN_T) void scan_deg(
    const int* __restrict__ deg, int* __restrict__ rowptr,
    int* __restrict__ cursor, const int* __restrict__ flag)
{
    if (*flag == 0) return;
    __shared__ int sums[SCAN_T];
    const int t = threadIdx.x;
    const int base = t * SCAN_CH;

    int v[SCAN_CH];
    const int4* dp = reinterpret_cast<const int4*>(deg + base);
#pragma unroll
    for (int j = 0; j < SCAN_CH / 4; j++) {
        int4 q = dp[j];
        v[4 * j + 0] = q.x; v[4 * j + 1] = q.y;
        v[4 * j + 2] = q.z; v[4 * j + 3] = q.w;
    }
    int s = 0;
#pragma unroll
    for (int j = 0; j < SCAN_CH; j++) s += v[j];
    sums[t] = s;
    __syncthreads();
    for (int off = 1; off < SCAN_T; off <<= 1) {
        int x = (t >= off) ? sums[t - off] : 0;
        __syncthreads();
        sums[t] += x;
        __syncthreads();
    }
    int run = sums[t] - s;
    if (t == 0) rowptr[0] = 0;
#pragma unroll
    for (int j = 0; j < SCAN_CH; j++) {
        cursor[base + j] = run;
        run += v[j];
        rowptr[base + j + 1] = run;
    }
}

// ---------------------------------------------------------------------------
// Merged: scatter_edges (blocks [0, eb)) + L1 attention dots (blocks [eb, ...)).
// The two halves are independent (no ordering needed).
// ---------------------------------------------------------------------------
__global__ __launch_bounds__(256) void scatter_attx(
    const int* __restrict__ ei, int* __restrict__ cursor,
    int* __restrict__ csr_src, int E_, int eb,
    const float* __restrict__ x, const float* __restrict__ u1s,
    const float* __restrict__ u1d, float* __restrict__ as_out,
    float* __restrict__ ad_out, const int* __restrict__ flag)
{
    if (*flag == 0) return;
    const int b = blockIdx.x;
    if (b < eb) {
        int e = b * 256 + threadIdx.x;
        int tot = E_ + NODES;
        if (e >= tot) return;
        int src, dst;
        if (e < E_) { src = ei[e]; dst = ei[E_ + e]; }
        else        { src = e - E_; dst = src; }
        int pos = atomicAdd(&cursor[dst], 1);
        csr_src[pos] = src;
    } else {
        const int wid  = threadIdx.x >> 6;
        const int lane = threadIdx.x & 63;
        const int node = (b - eb) * 4 + wid;
        if (node >= NODES) return;
        float v = x[(size_t)node * 64 + lane];
        float ps[2], pd[2];
#pragma unroll
        for (int h = 0; h < 2; h++) {
            ps[h] = v * u1s[h * 64 + lane];
            pd[h] = v * u1d[h * 64 + lane];
        }
#pragma unroll
        for (int off = 32; off; off >>= 1) {
#pragma unroll
            for (int h = 0; h < 2; h++) {
                ps[h] += __shfl_xor(ps[h], off);
                pd[h] += __shfl_xor(pd[h], off);
            }
        }
        if (lane == 0) {
#pragma unroll
            for (int h = 0; h < 2; h++) {
                as_out[node * 2 + h] = ps[h];
                ad_out[node * 2 + h] = pd[h];
            }
        }
    }
}

// ---------------------------------------------------------------------------
// MFMA GEMM: out[n, z*M + ct*16 + c] = Xb[n, z*K + k] @ Wb[z*M + m, k]^T
// bf16 in, fp32 accumulate. One 16x16 C tile per wave, LDS-free.
// C frag: col = lane&15, row = (lane>>4)*4 + i  (m89-verified).
// Optional fused attention dots (heads==1) via atomics on zeroed buffers.
// ---------------------------------------------------------------------------
template <int K, int M, int OUT_BF16, int RELU, int DOTS>
__global__ __launch_bounds__(256) void gemm_mfma(
    const unsigned short* __restrict__ Xb, int ldx,
    const unsigned short* __restrict__ Wb,
    const float* __restrict__ bias,
    void* __restrict__ outv, int ldc,
    const float* __restrict__ att_s, const float* __restrict__ att_d,
    float* __restrict__ as_out, float* __restrict__ ad_out,
    const int* __restrict__ flag, int Nrows)
{
    if (*flag == 0) return;
    constexpr int KC = K / 32;
    const int w    = threadIdx.x >> 6;
    const int lane = threadIdx.x & 63;
    const int z    = blockIdx.z;
    const int ct   = blockIdx.y;
    const int rowBase = blockIdx.x * 64 + w * 16;

    const int lr = lane & 15;
    const int lk = (lane >> 4) * 8;

    const int arow = min(rowBase + lr, Nrows - 1);
    const unsigned short* ap = Xb + (size_t)arow * ldx + z * K + lk;
    short8b a[KC];
#pragma unroll
    for (int kc = 0; kc < KC; kc++)
        a[kc] = *reinterpret_cast<const short8b*>(ap + kc * 32);

    const unsigned short* bp = Wb + (size_t)(z * M + ct * 16 + lr) * K + lk;
    short8b b[KC];
#pragma unroll
    for (int kc = 0; kc < KC; kc++)
        b[kc] = *reinterpret_cast<const short8b*>(bp + kc * 32);

    floatx4 c = {0.f, 0.f, 0.f, 0.f};
#pragma unroll
    for (int kc = 0; kc < KC; kc++)
        c = __builtin_amdgcn_mfma_f32_16x16x32_bf16(a[kc], b[kc], c, 0, 0, 0);

    const int colg = z * M + ct * 16 + lr;
    const float bv = bias ? bias[colg] : 0.f;

#pragma unroll
    for (int i = 0; i < 4; i++) {
        int r = rowBase + (lane >> 4) * 4 + i;
        float v = c[i] + bv;
        if (RELU) v = fmaxf(v, 0.f);
        if (r < Nrows) {
            if (OUT_BF16)
                ((unsigned short*)outv)[(size_t)r * ldc + colg] = f2bf(v);
            else
                ((float*)outv)[(size_t)r * ldc + colg] = v;
        }
    }

    if (DOTS) {  // partial row-dot over this tile's 16 cols (fp32 c) -> atomic
        const float as_v = att_s[colg];
        const float ad_v = att_d[colg];
#pragma unroll
        for (int i = 0; i < 4; i++) {
            int r = rowBase + (lane >> 4) * 4 + i;
            float ps = c[i] * as_v;
            float pd = c[i] * ad_v;
#pragma unroll
            for (int off = 8; off; off >>= 1) {
                ps += __shfl_xor(ps, off);
                pd += __shfl_xor(pd, off);
            }
            if (lr == 0 && r < Nrows) {
                atomicAdd(&as_out[r], ps);
                atomicAdd(&ad_out[r], pd);
            }
        }
    }
}

// ---------------------------------------------------------------------------
// fp32 GEMM (dense / use_neighbors==0 path only).
// ---------------------------------------------------------------------------
__global__ __launch_bounds__(256) void gemm_xwt(
    const float* __restrict__ X, int lda, const float* __restrict__ W,
    const float* __restrict__ bias, float* __restrict__ out, int ldc,
    int Nrows, int M, int K, int relu,
    const int* __restrict__ flag, int wantFlag)
{
    if (((*flag != 0) ? 1 : 0) != wantFlag) return;

    const int z = blockIdx.z;
    X += (size_t)z * K;
    W += (size_t)z * M * K;
    if (bias) bias += (size_t)z * M;
    out += (size_t)z * M;

    __shared__ float As[16][68];
    __shared__ float Bs[16][68];

    const int t  = threadIdx.x;
    const int tx = t & 15;
    const int ty = t >> 4;
    const int rowBase = blockIdx.y * 64;
    const int colBase = blockIdx.x * 64;

    float acc[4][4];
#pragma unroll
    for (int i = 0; i < 4; i++)
#pragma unroll
        for (int j = 0; j < 4; j++) acc[i][j] = 0.f;

    const int r_ld = t >> 2;
    const int k_ld = (t & 3) * 4;

    for (int kt = 0; kt < K; kt += 16) {
        float4 av = make_float4(0.f, 0.f, 0.f, 0.f);
        int grow = rowBase + r_ld;
        if (grow < Nrows)
            av = *reinterpret_cast<const float4*>(&X[(size_t)grow * lda + kt + k_ld]);
        As[k_ld + 0][r_ld] = av.x;
        As[k_ld + 1][r_ld] = av.y;
        As[k_ld + 2][r_ld] = av.z;
        As[k_ld + 3][r_ld] = av.w;
        float4 bv = make_float4(0.f, 0.f, 0.f, 0.f);
        int gm = colBase + r_ld;
        if (gm < M)
            bv = *reinterpret_cast<const float4*>(&W[(size_t)gm * K + kt + k_ld]);
        Bs[k_ld + 0][r_ld] = bv.x;
        Bs[k_ld + 1][r_ld] = bv.y;
        Bs[k_ld + 2][r_ld] = bv.z;
        Bs[k_ld + 3][r_ld] = bv.w;
        __syncthreads();

#pragma unroll
        for (int kk = 0; kk < 16; ++kk) {
            const float4 a = *reinterpret_cast<const float4*>(&As[kk][ty * 4]);
            const float4 b = *reinterpret_cast<const float4*>(&Bs[kk][tx * 4]);
            acc[0][0] += a.x * b.x; acc[0][1] += a.x * b.y; acc[0][2] += a.x * b.z; acc[0][3] += a.x * b.w;
            acc[1][0] += a.y * b.x; acc[1][1] += a.y * b.y; acc[1][2] += a.y * b.z; acc[1][3] += a.y * b.w;
            acc[2][0] += a.z * b.x; acc[2][1] += a.z * b.y; acc[2][2] += a.z * b.z; acc[2][3] += a.z * b.w;
            acc[3][0] += a.w * b.x; acc[3][1] += a.w * b.y; acc[3][2] += a.w * b.z; acc[3][3] += a.w * b.w;
        }
        __syncthreads();
    }

#pragma unroll
    for (int i = 0; i < 4; i++) {
        int row = rowBase + ty * 4 + i;
        if (row >= Nrows) continue;
        int col0 = colBase + tx * 4;
        if (col0 >= M) continue;
        float4 v = make_float4(acc[i][0], acc[i][1], acc[i][2], acc[i][3]);
        if (bias) {
            v.x += bias[col0 + 0]; v.y += bias[col0 + 1];
            v.z += bias[col0 + 2]; v.w += bias[col0 + 3];
        }
        if (relu) {
            v.x = fmaxf(v.x, 0.f); v.y = fmaxf(v.y, 0.f);
            v.z = fmaxf(v.z, 0.f); v.w = fmaxf(v.w, 0.f);
        }
        *reinterpret_cast<float4*>(&out[(size_t)row * ldc + col0]) = v;
    }
}

// ---------------------------------------------------------------------------
// GAT aggregation of bf16 RAW features (layers 1/3) -> bf16 output.
// Fast path (deg <= 64): one edge/lane; weight AND source index live in lane
// registers, fetched via __shfl (wave-uniform loop, all source lanes active).
// ---------------------------------------------------------------------------
template <int K, int HH>
__global__ __launch_bounds__(256) void gat_aggr_x(
    const unsigned short* __restrict__ xb, const float* __restrict__ as_,
    const float* __restrict__ ad_, const int* __restrict__ rowptr,
    const int* __restrict__ csr_src, unsigned short* __restrict__ aggb,
    const int* __restrict__ flag)
{
    if (*flag == 0) return;
    const int node = blockIdx.x * 4 + (threadIdx.x >> 6);
    const int lane = threadIdx.x & 63;
    if (node >= NODES) return;

    const int beg = rowptr[node], end = rowptr[node + 1];
    const int deg = end - beg;

    float adv[HH];
#pragma unroll
    for (int h = 0; h < HH; h++) adv[h] = ad_[node * HH + h];

    float wl[HH];
    float mx[HH], rden[HH];
    int s_l = 0;
    const bool fast = (deg <= WAVE);

    if (fast) {
        float e[HH];
        int i = beg + lane;
        if (i < end) {
            s_l = csr_src[i];
#pragma unroll
            for (int h = 0; h < HH; h++)
                e[h] = lrelu(as_[s_l * HH + h] + adv[h]);
        } else {
#pragma unroll
            for (int h = 0; h < HH; h++) e[h] = -1e30f;
        }
#pragma unroll
        for (int h = 0; h < HH; h++) {
            mx[h] = e[h];
#pragma unroll
            for (int off = 32; off; off >>= 1)
                mx[h] = fmaxf(mx[h], __shfl_xor(mx[h], off));
            float ex = __expf(e[h] - mx[h]);
            wl[h] = ex;
            float dn = ex;
#pragma unroll
            for (int off = 32; off; off >>= 1)
                dn += __shfl_xor(dn, off);
            rden[h] = 1.f / dn;
        }
    } else {
        float den[HH];
#pragma unroll
        for (int h = 0; h < HH; h++) { mx[h] = -1e30f; den[h] = 0.f; }
        for (int i = beg + lane; i < end; i += WAVE) {
            int s = csr_src[i];
#pragma unroll
            for (int h = 0; h < HH; h++)
                mx[h] = fmaxf(mx[h], lrelu(as_[s * HH + h] + adv[h]));
        }
#pragma unroll
        for (int h = 0; h < HH; h++)
#pragma unroll
            for (int off = 32; off; off >>= 1)
                mx[h] = fmaxf(mx[h], __shfl_xor(mx[h], off));
        for (int i = beg + lane; i < end; i += WAVE) {
            int s = csr_src[i];
#pragma unroll
            for (int h = 0; h < HH; h++)
                den[h] += __expf(lrelu(as_[s * HH + h] + adv[h]) - mx[h]);
        }
#pragma unroll
        for (int h = 0; h < HH; h++) {
#pragma unroll
            for (int off = 32; off; off >>= 1)
                den[h] += __shfl_xor(den[h], off);
            rden[h] = 1.f / den[h];
        }
    }

    constexpr int LPG = K / 8;          // lanes per edge, 8 bf16 (16B) each
    constexpr int GR  = WAVE / LPG;     // edges in flight per iter
    const int esub = lane / LPG;
    const int c8   = lane % LPG;

    float acc[HH][8];
#pragma unroll
    for (int h = 0; h < HH; h++)
#pragma unroll
        for (int j = 0; j < 8; j++) acc[h][j] = 0.f;

    if (fast) {
        const int iters = (deg + GR - 1) / GR;   // wave-uniform
        for (int it = 0; it < iters; ++it) {
            const int i = beg + it * GR + esub;
            const bool valid = (i < end);
            const int srcl = valid ? (i - beg) : 0;
            int s = __shfl(s_l, srcl);           // index from register
            float w[HH];
#pragma unroll
            for (int h = 0; h < HH; h++)
                w[h] = __shfl(wl[h], srcl);
            if (valid) {
                uint4 q = *reinterpret_cast<const uint4*>(&xb[(size_t)s * K + c8 * 8]);
                float v[8];
                unpack8(q, v);
#pragma unroll
                for (int h = 0; h < HH; h++)
#pragma unroll
                    for (int j = 0; j < 8; j++)
                        acc[h][j] += v[j] * w[h];
            }
        }
    } else {
        for (int i = beg + esub; i < end; i += GR) {
            int s = csr_src[i];
            float w[HH];
#pragma unroll
            for (int h = 0; h < HH; h++)
                w[h] = __expf(lrelu(as_[s * HH + h] + adv[h]) - mx[h]);
            uint4 q = *reinterpret_cast<const uint4*>(&xb[(size_t)s * K + c8 * 8]);
            float v[8];
            unpack8(q, v);
#pragma unroll
            for (int h = 0; h < HH; h++)
#pragma unroll
                for (int j = 0; j < 8; j++)
                    acc[h][j] += v[j] * w[h];
        }
    }
#pragma unroll
    for (int off = LPG; off < WAVE; off <<= 1)
#pragma unroll
        for (int h = 0; h < HH; h++)
#pragma unroll
            for (int j = 0; j < 8; j++)
                acc[h][j] += __shfl_xor(acc[h][j], off);

    if (esub == 0) {
#pragma unroll
        for (int h = 0; h < HH; h++) {
            float o[8];
#pragma unroll
            for (int j = 0; j < 8; j++) o[j] = acc[h][j] * rden[h];
            *reinterpret_cast<uint4*>(&aggb[(size_t)node * (HH * K) + h * K + c8 * 8]) = pack8(o);
        }
    }
}

// ---------------------------------------------------------------------------
// GAT aggregation of bf16 PROJECTED features (layers 2/4), +bias (+relu).
// fp32 out, optional bf16 shadow, optional fused NEXT-layer attention dots
// (DOTS3: asb[node,h] = out_row . u3s[h,:], 2 heads, 4-lane shfl reduce).
// ---------------------------------------------------------------------------
template <int HF, int RELU, int OUTB, int DOTS3>
__global__ __launch_bounds__(256) void gat_aggr_h(
    const unsigned short* __restrict__ hb, const float* __restrict__ as_,
    const float* __restrict__ ad_, const int* __restrict__ rowptr,
    const int* __restrict__ csr_src, const float* __restrict__ bias,
    float* __restrict__ out, unsigned short* __restrict__ outb,
    const float* __restrict__ u3s, const float* __restrict__ u3d,
    float* __restrict__ as3o, float* __restrict__ ad3o,
    const int* __restrict__ flag)
{
    if (*flag == 0) return;
    const int node = blockIdx.x * 4 + (threadIdx.x >> 6);
    const int lane = threadIdx.x & 63;
    if (node >= NODES) return;

    const int beg = rowptr[node], end = rowptr[node + 1];
    const int deg = end - beg;
    const float adv = ad_[node];

    float wl, mx, rden;
    int s_l = 0;
    const bool fast = (deg <= WAVE);

    if (fast) {
        int i = beg + lane;
        float e = -1e30f;
        if (i < end) {
            s_l = csr_src[i];
            e = lrelu(as_[s_l] + adv);
        }
        mx = e;
#pragma unroll
        for (int off = 32; off; off >>= 1)
            mx = fmaxf(mx, __shfl_xor(mx, off));
        wl = __expf(e - mx);
        float dn = wl;
#pragma unroll
        for (int off = 32; off; off >>= 1)
            dn += __shfl_xor(dn, off);
        rden = 1.f / dn;
    } else {
        mx = -1e30f;
        float den = 0.f;
        for (int i = beg + lane; i < end; i += WAVE) {
            int s = csr_src[i];
            mx = fmaxf(mx, lrelu(as_[s] + adv));
        }
#pragma unroll
        for (int off = 32; off; off >>= 1)
            mx = fmaxf(mx, __shfl_xor(mx, off));
        for (int i = beg + lane; i < end; i += WAVE) {
            int s = csr_src[i];
            den += __expf(lrelu(as_[s] + adv) - mx);
        }
#pragma unroll
        for (int off = 32; off; off >>= 1)
            den += __shfl_xor(den, off);
        rden = 1.f / den;
        wl = 0.f;
    }

    constexpr int LPG = HF / 8;
    constexpr int GR  = WAVE / LPG;
    const int esub = lane / LPG;
    const int c8   = lane % LPG;

    float acc[8];
#pragma unroll
    for (int j = 0; j < 8; j++) acc[j] = 0.f;

    if (fast) {
        const int iters = (deg + GR - 1) / GR;   // wave-uniform
        for (int it = 0; it < iters; ++it) {
            const int i = beg + it * GR + esub;
            const bool valid = (i < end);
            const int srcl = valid ? (i - beg) : 0;
            int s = __shfl(s_l, srcl);
            float w = __shfl(wl, srcl);
            if (valid) {
                uint4 q = *reinterpret_cast<const uint4*>(&hb[(size_t)s * HF + c8 * 8]);
                float v[8];
                unpack8(q, v);
#pragma unroll
                for (int j = 0; j < 8; j++) acc[j] += v[j] * w;
            }
        }
    } else {
        for (int i = beg + esub; i < end; i += GR) {
            int s = csr_src[i];
            float w = __expf(lrelu(as_[s] + adv) - mx);
            uint4 q = *reinterpret_cast<const uint4*>(&hb[(size_t)s * HF + c8 * 8]);
            float v[8];
            unpack8(q, v);
#pragma unroll
            for (int j = 0; j < 8; j++) acc[j] += v[j] * w;
        }
    }
#pragma unroll
    for (int off = LPG; off < WAVE; off <<= 1)
#pragma unroll
        for (int j = 0; j < 8; j++)
            acc[j] += __shfl_xor(acc[j], off);

    if (esub == 0) {
        const int col0 = c8 * 8;
        float o[8];
#pragma unroll
        for (int j = 0; j < 8; j++) {
            o[j] = acc[j] * rden + bias[col0 + j];
            if (RELU) o[j] = fmaxf(o[j], 0.f);
        }
        float4 o0 = make_float4(o[0], o[1], o[2], o[3]);
        float4 o1 = make_float4(o[4], o[5], o[6], o[7]);
        *reinterpret_cast<float4*>(&out[(size_t)node * HF + col0]) = o0;
        *reinterpret_cast<float4*>(&out[(size_t)node * HF + col0 + 4]) = o1;
        if (OUTB)
            *reinterpret_cast<uint4*>(&outb[(size_t)node * HF + col0]) = pack8(o);
        if (DOTS3) {
            // lanes 0..LPG-1 all active here (esub==0 <=> lane < LPG);
            // shfl_xor with off < LPG stays within the active group.
            float ps[2], pd[2];
#pragma unroll
            for (int h = 0; h < 2; h++) {
                float s1 = 0.f, s2 = 0.f;
#pragma unroll
                for (int j = 0; j < 8; j++) {
                    s1 += o[j] * u3s[h * HF + col0 + j];
                    s2 += o[j] * u3d[h * HF + col0 + j];
                }
                ps[h] = s1; pd[h] = s2;
            }
#pragma unroll
            for (int off = 1; off < LPG; off <<= 1) {
#pragma unroll
                for (int h = 0; h < 2; h++) {
                    ps[h] += __shfl_xor(ps[h], off);
                    pd[h] += __shfl_xor(pd[h], off);
                }
            }
            if (lane == 0) {
#pragma unroll
                for (int h = 0; h < 2; h++) {
                    as3o[node * 2 + h] = ps[h];
                    ad3o[node * 2 + h] = pd[h];
                }
            }
        }
    }
}

// ---------------------------------------------------------------------------
extern "C" void kernel_launch(void* const* d_in, const int* in_sizes, int n_in,
                              void* d_out, int out_size, void* d_ws, size_t ws_size,
                              hipStream_t stream)
{
    const float* x    = (const float*)d_in[0];
    const int*   ei   = (const int*)d_in[1];
    const int*   flag = (const int*)d_in[2];
    const float* W1 = (const float*)d_in[3];
    const float* as1 = (const float*)d_in[4];
    const float* ad1 = (const float*)d_in[5];
    const float* b1 = (const float*)d_in[6];
    const float* W2 = (const float*)d_in[7];
    const float* as2 = (const float*)d_in[8];
    const float* ad2 = (const float*)d_in[9];
    const float* b2 = (const float*)d_in[10];
    const float* W3 = (const float*)d_in[11];
    const float* as3 = (const float*)d_in[12];
    const float* ad3 = (const float*)d_in[13];
    const float* b3 = (const float*)d_in[14];
    const float* W4 = (const float*)d_in[15];
    const float* as4 = (const float*)d_in[16];
    const float* ad4 = (const float*)d_in[17];
    const float* b4 = (const float*)d_in[18];
    const float* el1w = (const float*)d_in[19];
    const float* el1b = (const float*)d_in[20];
    const float* el2w = (const float*)d_in[21];
    const float* el2b = (const float*)d_in[22];
    const float* dl1w = (const float*)d_in[23];
    const float* dl1b = (const float*)d_in[24];
    const float* dl2w = (const float*)d_in[25];
    const float* dl2b = (const float*)d_in[26];

    const int E_   = in_sizes[1] / 2;
    const int Etot = E_ + NODES;

    char* base = (char*)d_ws;
    size_t off = 0;
    auto carve = [&](size_t bytes) -> void* {
        void* p = base + off;
        off = (off + bytes + 255) & ~(size_t)255;
        return p;
    };
    float* T0  = (float*)carve((size_t)NODES * 128 * 4);   // dense intermediate
    float* A   = (float*)carve((size_t)NODES * 256 * 4);   // dense intermediate
    float* Bz  = (float*)carve((size_t)NODES * 32 * 4);    // z (fp32)
    float* asb = (float*)carve((size_t)NODES * 2 * 4);     // L1/L3 dots
    float* adb = (float*)carve((size_t)NODES * 2 * 4);
    float* as2b = (float*)carve((size_t)NODES * 4);        // L2 dots (atomic)
    float* ad2b = (float*)carve((size_t)NODES * 4);
    float* as4b = (float*)carve((size_t)NODES * 4);        // L4 dots (atomic)
    float* ad4b = (float*)carve((size_t)NODES * 4);
    float* u1s = (float*)carve(2 * 64 * 4);
    float* u1d = (float*)carve(2 * 64 * 4);
    float* u3s = (float*)carve(2 * 32 * 4);
    float* u3d = (float*)carve(2 * 32 * 4);
    unsigned short* xb   = (unsigned short*)carve((size_t)NODES * 64 * 2);   // bf16 x
    unsigned short* aggb = (unsigned short*)carve((size_t)NODES * 128 * 2);  // bf16 agg
    unsigned short* Ab   = (unsigned short*)carve((size_t)NODES * 256 * 2);  // bf16 L1/L3 out
    unsigned short* T1b  = (unsigned short*)carve((size_t)NODES * 64 * 2);   // bf16 h2/h4
    unsigned short* Bzb  = (unsigned short*)carve((size_t)NODES * 32 * 2);   // bf16 z
    unsigned short* wb1  = (unsigned short*)carve(256 * 64 * 2);
    unsigned short* wb2  = (unsigned short*)carve(32 * 256 * 2);
    unsigned short* wb3  = (unsigned short*)carve(256 * 32 * 2);
    unsigned short* wb4  = (unsigned short*)carve(64 * 256 * 2);
    int* deg    = (int*)carve((size_t)SCAN_CAP * 4);
    int* rowptr = (int*)carve((size_t)(SCAN_CAP + 1) * 4);
    int* cursor = (int*)carve((size_t)SCAN_CAP * 4);
    int* csr    = (int*)carve((size_t)Etot * 4);
    (void)ws_size; (void)n_in; (void)out_size;

    float* outp = (float*)d_out;

    const int nodeBlocks = (NODES + 3) / 4;
    const int edgeBlocks = (Etot + 255) / 256;
    dim3 blk(256);
    const int rowTiles = (NODES + 63) / 64;   // 469

    // ---- chain head: zero deg (memset node), fused prep, scan, scatter+attL1 ----
    hipMemsetAsync(deg, 0, (size_t)SCAN_CAP * 4, stream);
    prep2<<<2048, 256, 0, stream>>>(ei, E_, deg, as2b, ad2b, as4b, ad4b,
                                    W1, wb1, W2, wb2, W3, wb3, W4, wb4,
                                    x, xb, as1, ad1, u1s, u1d,
                                    as3, ad3, u3s, u3d, flag);
    scan_deg<<<1, SCAN_T, 0, stream>>>(deg, rowptr, cursor, flag);
    scatter_attx<<<edgeBlocks + nodeBlocks, blk, 0, stream>>>(
        ei, cursor, csr, E_, edgeBlocks, x, u1s, u1d, asb, adb, flag);

    // ---- Layer 1: GAT(64 -> 128 x 2 heads) + ReLU [aggregate-then-project] ----
    gat_aggr_x<64, 2><<<nodeBlocks, blk, 0, stream>>>(xb, asb, adb, rowptr, csr, aggb, flag);
    gemm_mfma<64, 128, 1, 1, 0><<<dim3(rowTiles, 8, 2), blk, 0, stream>>>(
        aggb, 128, wb1, b1, Ab, 256, nullptr, nullptr, nullptr, nullptr, flag, NODES);

    // ---- Layer 2: MFMA gemm (bf16 out + atomic dots); aggr fuses L3 dots ----
    gemm_mfma<256, 32, 1, 0, 1><<<dim3(rowTiles, 2, 1), blk, 0, stream>>>(
        Ab, 256, wb2, nullptr, T1b, 32, as2, ad2, as2b, ad2b, flag, NODES);
    gat_aggr_h<32, 0, 1, 1><<<nodeBlocks, blk, 0, stream>>>(
        T1b, as2b, ad2b, rowptr, csr, b2, Bz, Bzb, u3s, u3d, asb, adb, flag);

    // ---- Layer 3: GAT(32 -> 128 x 2 heads) + ReLU [aggregate-then-project] ----
    gat_aggr_x<32, 2><<<nodeBlocks, blk, 0, stream>>>(Bzb, asb, adb, rowptr, csr, aggb, flag);
    gemm_mfma<32, 128, 1, 1, 0><<<dim3(rowTiles, 8, 2), blk, 0, stream>>>(
        aggb, 64, wb3, b3, Ab, 256, nullptr, nullptr, nullptr, nullptr, flag, NODES);

    // ---- Layer 4: MFMA gemm (bf16 out + atomic dots); aggr -> output ----
    gemm_mfma<256, 64, 1, 0, 1><<<dim3(rowTiles, 4, 1), blk, 0, stream>>>(
        Ab, 256, wb4, nullptr, T1b, 64, as4, ad4, as4b, ad4b, flag, NODES);
    gat_aggr_h<64, 0, 0, 0><<<nodeBlocks, blk, 0, stream>>>(
        T1b, as4b, ad4b, rowptr, csr, b4, outp, nullptr, nullptr, nullptr,
        nullptr, nullptr, flag);

    // ---- Dense path (use_neighbors == 0), fp32, unchanged ----
    gemm_xwt<<<dim3(2, rowTiles, 1), blk, 0, stream>>>(x,  64,  el1w, el1b, T0,   128, NODES, 128, 64, 1, flag, 0);
    gemm_xwt<<<dim3(1, rowTiles, 1), blk, 0, stream>>>(T0, 128, el2w, el2b, Bz,   32,  NODES, 32, 128, 0, flag, 0);
    gemm_xwt<<<dim3(2, rowTiles, 1), blk, 0, stream>>>(Bz, 32,  dl1w, dl1b, A,    128, NODES, 128, 32, 1, flag, 0);
    gemm_xwt<<<dim3(1, rowTiles, 1), blk, 0, stream>>>(A,  128, dl2w, dl2b, outp, 64,  NODES, 64, 128, 0, flag, 0);
}

// Round 12
// 338.234 us; speedup vs baseline: 1.1429x; 1.0968x over previous
//
#include <hip/hip_runtime.h>
#include <hip/hip_bf16.h>
#include <math.h>

#define NODES 30000
#define WAVE 64
#define SCAN_T 1024
#define SCAN_CH 32
#define SCAN_CAP (SCAN_T * SCAN_CH)   // 32768 >= NODES, branchless scan

typedef __attribute__((ext_vector_type(8))) short short8b;   // 8 bf16 (4 VGPRs)
typedef __attribute__((ext_vector_type(4))) float floatx4;   // MFMA C/D

static __device__ __forceinline__ float lrelu(float x) {
    return (x > 0.f) ? x : 0.2f * x;
}

// fp32 -> bf16 round-to-nearest-even
static __device__ __forceinline__ unsigned short f2bf(float f) {
    union { float f; unsigned u; } v; v.f = f;
    unsigned r = v.u + 0x7FFF + ((v.u >> 16) & 1);
    return (unsigned short)(r >> 16);
}

// unpack 8 bf16 (uint4) -> 8 floats
static __device__ __forceinline__ void unpack8(uint4 q, float* v) {
    v[0] = __uint_as_float(q.x << 16); v[1] = __uint_as_float(q.x & 0xFFFF0000u);
    v[2] = __uint_as_float(q.y << 16); v[3] = __uint_as_float(q.y & 0xFFFF0000u);
    v[4] = __uint_as_float(q.z << 16); v[5] = __uint_as_float(q.z & 0xFFFF0000u);
    v[6] = __uint_as_float(q.w << 16); v[7] = __uint_as_float(q.w & 0xFFFF0000u);
}

// pack 8 floats -> 8 bf16 (uint4)
static __device__ __forceinline__ uint4 pack8(const float* v) {
    uint4 p;
    p.x = (unsigned)f2bf(v[0]) | ((unsigned)f2bf(v[1]) << 16);
    p.y = (unsigned)f2bf(v[2]) | ((unsigned)f2bf(v[3]) << 16);
    p.z = (unsigned)f2bf(v[4]) | ((unsigned)f2bf(v[5]) << 16);
    p.w = (unsigned)f2bf(v[6]) | ((unsigned)f2bf(v[7]) << 16);
    return p;
}

// ---------------------------------------------------------------------------
// fold body: u[h,k] = sum_f att[h,f] * W[h*F+f, k]  (one block per (sel,h))
// ---------------------------------------------------------------------------
template <int HH, int F, int K>
static __device__ void fold_body(
    const float* __restrict__ W, const float* __restrict__ as_,
    const float* __restrict__ ad_, float* __restrict__ us,
    float* __restrict__ ud, int b, float* red)
{
    const int sel = b / HH;
    const int h   = b % HH;
    const float* att = sel ? ad_ : as_;
    float* uo = sel ? ud : us;

    constexpr int NG = 256 / K;
    const int k  = threadIdx.x % K;
    const int fg = threadIdx.x / K;

    float s = 0.f;
#pragma unroll
    for (int f = fg; f < F; f += NG)
        s += att[h * F + f] * W[(size_t)(h * F + f) * K + k];

    red[threadIdx.x] = s;
    __syncthreads();
    if (fg == 0) {
        float tot = s;
#pragma unroll
        for (int g = 1; g < NG; g++) tot += red[g * K + k];
        uo[h * K + k] = tot;
    }
}

// ---------------------------------------------------------------------------
// Fused prep (GAT path): count_deg atomics WITH rank capture (deg pre-zeroed
// via memset), zero dots buffers, cvt weights & x to bf16, fold L1/L3 att
// vectors (blocks 0-7 extra duty).
// ---------------------------------------------------------------------------
__global__ __launch_bounds__(256) void prep2(
    const int* __restrict__ ei, int E_, int* __restrict__ deg,
    int* __restrict__ rank,
    float* __restrict__ z0, float* __restrict__ z1,
    float* __restrict__ z2, float* __restrict__ z3,
    const float* __restrict__ W1, unsigned short* __restrict__ wb1,
    const float* __restrict__ W2, unsigned short* __restrict__ wb2,
    const float* __restrict__ W3, unsigned short* __restrict__ wb3,
    const float* __restrict__ W4, unsigned short* __restrict__ wb4,
    const float* __restrict__ x, unsigned short* __restrict__ xb,
    const float* __restrict__ as1, const float* __restrict__ ad1,
    float* __restrict__ u1s, float* __restrict__ u1d,
    const float* __restrict__ as3, const float* __restrict__ ad3,
    float* __restrict__ u3s, float* __restrict__ u3d,
    const int* __restrict__ flag)
{
    if (*flag == 0) return;
    __shared__ float red[256];
    const int tid = blockIdx.x * blockDim.x + threadIdx.x;
    const int stride = gridDim.x * blockDim.x;

    // degree count + per-edge rank (deg zeroed by preceding memset)
    const int tot = E_ + NODES;
    for (int e = tid; e < tot; e += stride) {
        int dst = (e < E_) ? ei[E_ + e] : (e - E_);
        rank[e] = atomicAdd(&deg[dst], 1);
    }
    for (int i = tid; i < NODES; i += stride) {
        z0[i] = 0.f; z1[i] = 0.f; z2[i] = 0.f; z3[i] = 0.f;
    }
    for (int i = tid; i < 256 * 64; i += stride) wb1[i] = f2bf(W1[i]);
    for (int i = tid; i < 32 * 256; i += stride) wb2[i] = f2bf(W2[i]);
    for (int i = tid; i < 256 * 32; i += stride) wb3[i] = f2bf(W3[i]);
    for (int i = tid; i < 64 * 256; i += stride) wb4[i] = f2bf(W4[i]);
    for (int i = tid; i < NODES * 64 / 4; i += stride) {
        float4 v = reinterpret_cast<const float4*>(x)[i];
        ushort4 o;
        o.x = f2bf(v.x); o.y = f2bf(v.y); o.z = f2bf(v.z); o.w = f2bf(v.w);
        reinterpret_cast<ushort4*>(xb)[i] = o;
    }

    // fold duty: blocks 0-3 = L1 (K=64), blocks 4-7 = L3 (K=32)
    if (blockIdx.x < 8) {
        __syncthreads();
        if (blockIdx.x < 4)
            fold_body<2, 128, 64>(W1, as1, ad1, u1s, u1d, blockIdx.x, red);
        else
            fold_body<2, 128, 32>(W3, as3, ad3, u3s, u3d, blockIdx.x - 4, red);
    }
}

// ---------------------------------------------------------------------------
// Branchless single-block scan over SCAN_CAP. Writes rowptr only.
// ---------------------------------------------------------------------------
__global__ __launch_bounds__(SCAN_T) void scan_deg(
    const int* __restrict__ deg, int* __restrict__ rowptr,
    const int* __restrict__ flag)
{
    if (*flag == 0) return;
    __shared__ int sums[SCAN_T];
    const int t = threadIdx.x;
    const int base = t * SCAN_CH;

    int v[SCAN_CH];
    const int4* dp = reinterpret_cast<const int4*>(deg + base);
#pragma unroll
    for (int j = 0; j < SCAN_CH / 4; j++) {
        int4 q = dp[j];
        v[4 * j + 0] = q.x; v[4 * j + 1] = q.y;
        v[4 * j + 2] = q.z; v[4 * j + 3] = q.w;
    }
    int s = 0;
#pragma unroll
    for (int j = 0; j < SCAN_CH; j++) s += v[j];
    sums[t] = s;
    __syncthreads();
    for (int off = 1; off < SCAN_T; off <<= 1) {
        int x = (t >= off) ? sums[t - off] : 0;
        __syncthreads();
        sums[t] += x;
        __syncthreads();
    }
    int run = sums[t] - s;
    if (t == 0) rowptr[0] = 0;
#pragma unroll
    for (int j = 0; j < SCAN_CH; j++) {
        run += v[j];
        rowptr[base + j + 1] = run;
    }
}

// ---------------------------------------------------------------------------
// Merged: rank-based scatter (NO atomics; blocks [0, eb)) + L1 attention
// dots (blocks [eb, ...)). The two halves are independent.
// ---------------------------------------------------------------------------
__global__ __launch_bounds__(256) void scatter_attx(
    const int* __restrict__ ei, const int* __restrict__ rowptr,
    const int* __restrict__ rank, int* __restrict__ csr_src, int E_, int eb,
    const float* __restrict__ x, const float* __restrict__ u1s,
    const float* __restrict__ u1d, float* __restrict__ as_out,
    float* __restrict__ ad_out, const int* __restrict__ flag)
{
    if (*flag == 0) return;
    const int b = blockIdx.x;
    if (b < eb) {
        int e = b * 256 + threadIdx.x;
        int tot = E_ + NODES;
        if (e >= tot) return;
        int src, dst;
        if (e < E_) { src = ei[e]; dst = ei[E_ + e]; }
        else        { src = e - E_; dst = src; }
        csr_src[rowptr[dst] + rank[e]] = src;
    } else {
        const int wid  = threadIdx.x >> 6;
        const int lane = threadIdx.x & 63;
        const int node = (b - eb) * 4 + wid;
        if (node >= NODES) return;
        float v = x[(size_t)node * 64 + lane];
        float ps[2], pd[2];
#pragma unroll
        for (int h = 0; h < 2; h++) {
            ps[h] = v * u1s[h * 64 + lane];
            pd[h] = v * u1d[h * 64 + lane];
        }
#pragma unroll
        for (int off = 32; off; off >>= 1) {
#pragma unroll
            for (int h = 0; h < 2; h++) {
                ps[h] += __shfl_xor(ps[h], off);
                pd[h] += __shfl_xor(pd[h], off);
            }
        }
        if (lane == 0) {
#pragma unroll
            for (int h = 0; h < 2; h++) {
                as_out[node * 2 + h] = ps[h];
                ad_out[node * 2 + h] = pd[h];
            }
        }
    }
}

// ---------------------------------------------------------------------------
// FUSED aggregate+project (layers 1/3): one 1024-thread block per 64 nodes.
// Phase A: 16 waves x 4 nodes each — per-node softmax (one edge/lane, weight
// & src index in registers, shfl-fetched, wave-uniform loop) + bf16 gather
// accumulate -> padded LDS tile [64][HH*K+8].
// Phase B: MFMA 64x(HH*128) from LDS A-frags + global W B-frags, +bias+relu,
// bf16 out. Per-block independence: a row block's GEMM needs only its own
// aggregated rows, so no global sync required.
// ---------------------------------------------------------------------------
template <int K, int HH, int M>
__global__ __launch_bounds__(1024) void aggx_gemm(
    const unsigned short* __restrict__ xb,
    const float* __restrict__ as_, const float* __restrict__ ad_,
    const int* __restrict__ rowptr, const int* __restrict__ csr_src,
    const unsigned short* __restrict__ Wb, const float* __restrict__ bias,
    unsigned short* __restrict__ outb, const int* __restrict__ flag)
{
    if (*flag == 0) return;
    constexpr int LDSW = HH * K + 8;          // +8 bf16 pad: 16B-aligned rows
    __shared__ unsigned short agg[64][LDSW];

    const int wid  = threadIdx.x >> 6;        // 0..15
    const int lane = threadIdx.x & 63;
    const int nb   = blockIdx.x * 64;

    constexpr int LPG = K / 8;                // lanes per edge (8 bf16 each)
    constexpr int GR  = WAVE / LPG;           // edges in flight per iter
    const int esub = lane / LPG;
    const int c8   = lane % LPG;

    // ---- Phase A: aggregate 4 nodes per wave ----
    for (int nn = 0; nn < 4; ++nn) {
        const int nl = wid * 4 + nn;
        const int node = nb + nl;
        if (node >= NODES) {
            if (esub == 0) {
                uint4 zz = make_uint4(0u, 0u, 0u, 0u);
#pragma unroll
                for (int h = 0; h < HH; h++)
                    *reinterpret_cast<uint4*>(&agg[nl][h * K + c8 * 8]) = zz;
            }
            continue;
        }
        const int beg = rowptr[node], end = rowptr[node + 1];
        const int deg = end - beg;

        float adv[HH];
#pragma unroll
        for (int h = 0; h < HH; h++) adv[h] = ad_[node * HH + h];

        float wl[HH], mx[HH], rden[HH];
        int s_l = 0;
        const bool fast = (deg <= WAVE);

        if (fast) {
            float e[HH];
            int i = beg + lane;
            if (i < end) {
                s_l = csr_src[i];
#pragma unroll
                for (int h = 0; h < HH; h++)
                    e[h] = lrelu(as_[s_l * HH + h] + adv[h]);
            } else {
#pragma unroll
                for (int h = 0; h < HH; h++) e[h] = -1e30f;
            }
#pragma unroll
            for (int h = 0; h < HH; h++) {
                mx[h] = e[h];
#pragma unroll
                for (int off = 32; off; off >>= 1)
                    mx[h] = fmaxf(mx[h], __shfl_xor(mx[h], off));
                float ex = __expf(e[h] - mx[h]);
                wl[h] = ex;
                float dn = ex;
#pragma unroll
                for (int off = 32; off; off >>= 1)
                    dn += __shfl_xor(dn, off);
                rden[h] = 1.f / dn;
            }
        } else {
            float den[HH];
#pragma unroll
            for (int h = 0; h < HH; h++) { mx[h] = -1e30f; den[h] = 0.f; }
            for (int i = beg + lane; i < end; i += WAVE) {
                int s = csr_src[i];
#pragma unroll
                for (int h = 0; h < HH; h++)
                    mx[h] = fmaxf(mx[h], lrelu(as_[s * HH + h] + adv[h]));
            }
#pragma unroll
            for (int h = 0; h < HH; h++)
#pragma unroll
                for (int off = 32; off; off >>= 1)
                    mx[h] = fmaxf(mx[h], __shfl_xor(mx[h], off));
            for (int i = beg + lane; i < end; i += WAVE) {
                int s = csr_src[i];
#pragma unroll
                for (int h = 0; h < HH; h++)
                    den[h] += __expf(lrelu(as_[s * HH + h] + adv[h]) - mx[h]);
            }
#pragma unroll
            for (int h = 0; h < HH; h++) {
#pragma unroll
                for (int off = 32; off; off >>= 1)
                    den[h] += __shfl_xor(den[h], off);
                rden[h] = 1.f / den[h];
            }
        }

        float acc[HH][8];
#pragma unroll
        for (int h = 0; h < HH; h++)
#pragma unroll
            for (int j = 0; j < 8; j++) acc[h][j] = 0.f;

        if (fast) {
            const int iters = (deg + GR - 1) / GR;   // wave-uniform
            for (int it = 0; it < iters; ++it) {
                const int i = beg + it * GR + esub;
                const bool valid = (i < end);
                const int srcl = valid ? (i - beg) : 0;
                int s = __shfl(s_l, srcl);           // index from register
                float w[HH];
#pragma unroll
                for (int h = 0; h < HH; h++)
                    w[h] = __shfl(wl[h], srcl);
                if (valid) {
                    uint4 q = *reinterpret_cast<const uint4*>(&xb[(size_t)s * K + c8 * 8]);
                    float v[8];
                    unpack8(q, v);
#pragma unroll
                    for (int h = 0; h < HH; h++)
#pragma unroll
                        for (int j = 0; j < 8; j++)
                            acc[h][j] += v[j] * w[h];
                }
            }
        } else {
            for (int i = beg + esub; i < end; i += GR) {
                int s = csr_src[i];
                float w[HH];
#pragma unroll
                for (int h = 0; h < HH; h++)
                    w[h] = __expf(lrelu(as_[s * HH + h] + adv[h]) - mx[h]);
                uint4 q = *reinterpret_cast<const uint4*>(&xb[(size_t)s * K + c8 * 8]);
                float v[8];
                unpack8(q, v);
#pragma unroll
                for (int h = 0; h < HH; h++)
#pragma unroll
                    for (int j = 0; j < 8; j++)
                        acc[h][j] += v[j] * w[h];
            }
        }
#pragma unroll
        for (int off = LPG; off < WAVE; off <<= 1)
#pragma unroll
            for (int h = 0; h < HH; h++)
#pragma unroll
                for (int j = 0; j < 8; j++)
                    acc[h][j] += __shfl_xor(acc[h][j], off);

        if (esub == 0) {
#pragma unroll
            for (int h = 0; h < HH; h++) {
                float o[8];
#pragma unroll
                for (int j = 0; j < 8; j++) o[j] = acc[h][j] * rden[h];
                *reinterpret_cast<uint4*>(&agg[nl][h * K + c8 * 8]) = pack8(o);
            }
        }
    }
    __syncthreads();

    // ---- Phase B: MFMA from LDS ----
    constexpr int KC   = K / 32;
    constexpr int CTPH = M / 16;              // col tiles per head (8)
    const int lr = lane & 15;
    const int lk = (lane >> 4) * 8;
    const int z  = wid / CTPH;                // head
    const int mc = (wid % CTPH) * 16;         // col base within head

    const unsigned short* bp = Wb + (size_t)(z * M + mc + lr) * K + lk;
    short8b b[KC];
#pragma unroll
    for (int kc = 0; kc < KC; kc++)
        b[kc] = *reinterpret_cast<const short8b*>(bp + kc * 32);

    const int colg = z * M + mc + lr;
    const float bv = bias[colg];

#pragma unroll
    for (int rt = 0; rt < 4; ++rt) {
        short8b a[KC];
#pragma unroll
        for (int kc = 0; kc < KC; kc++)
            a[kc] = *reinterpret_cast<const short8b*>(&agg[rt * 16 + lr][z * K + lk + kc * 32]);
        floatx4 c = {0.f, 0.f, 0.f, 0.f};
#pragma unroll
        for (int kc = 0; kc < KC; kc++)
            c = __builtin_amdgcn_mfma_f32_16x16x32_bf16(a[kc], b[kc], c, 0, 0, 0);
#pragma unroll
        for (int i = 0; i < 4; i++) {
            int r = nb + rt * 16 + (lane >> 4) * 4 + i;
            float v = fmaxf(c[i] + bv, 0.f);  // L1/L3 always ReLU
            if (r < NODES)
                outb[(size_t)r * (HH * M) + colg] = f2bf(v);
        }
    }
}

// ---------------------------------------------------------------------------
// MFMA GEMM (layers 2/4): bf16 in, fp32 acc, bf16 out + fused atomic dots.
// ---------------------------------------------------------------------------
template <int K, int M, int OUT_BF16, int RELU, int DOTS>
__global__ __launch_bounds__(256) void gemm_mfma(
    const unsigned short* __restrict__ Xb, int ldx,
    const unsigned short* __restrict__ Wb,
    const float* __restrict__ bias,
    void* __restrict__ outv, int ldc,
    const float* __restrict__ att_s, const float* __restrict__ att_d,
    float* __restrict__ as_out, float* __restrict__ ad_out,
    const int* __restrict__ flag, int Nrows)
{
    if (*flag == 0) return;
    constexpr int KC = K / 32;
    const int w    = threadIdx.x >> 6;
    const int lane = threadIdx.x & 63;
    const int z    = blockIdx.z;
    const int ct   = blockIdx.y;
    const int rowBase = blockIdx.x * 64 + w * 16;

    const int lr = lane & 15;
    const int lk = (lane >> 4) * 8;

    const int arow = min(rowBase + lr, Nrows - 1);
    const unsigned short* ap = Xb + (size_t)arow * ldx + z * K + lk;
    short8b a[KC];
#pragma unroll
    for (int kc = 0; kc < KC; kc++)
        a[kc] = *reinterpret_cast<const short8b*>(ap + kc * 32);

    const unsigned short* bp = Wb + (size_t)(z * M + ct * 16 + lr) * K + lk;
    short8b b[KC];
#pragma unroll
    for (int kc = 0; kc < KC; kc++)
        b[kc] = *reinterpret_cast<const short8b*>(bp + kc * 32);

    floatx4 c = {0.f, 0.f, 0.f, 0.f};
#pragma unroll
    for (int kc = 0; kc < KC; kc++)
        c = __builtin_amdgcn_mfma_f32_16x16x32_bf16(a[kc], b[kc], c, 0, 0, 0);

    const int colg = z * M + ct * 16 + lr;
    const float bv = bias ? bias[colg] : 0.f;

#pragma unroll
    for (int i = 0; i < 4; i++) {
        int r = rowBase + (lane >> 4) * 4 + i;
        float v = c[i] + bv;
        if (RELU) v = fmaxf(v, 0.f);
        if (r < Nrows) {
            if (OUT_BF16)
                ((unsigned short*)outv)[(size_t)r * ldc + colg] = f2bf(v);
            else
                ((float*)outv)[(size_t)r * ldc + colg] = v;
        }
    }

    if (DOTS) {
        const float as_v = att_s[colg];
        const float ad_v = att_d[colg];
#pragma unroll
        for (int i = 0; i < 4; i++) {
            int r = rowBase + (lane >> 4) * 4 + i;
            float ps = c[i] * as_v;
            float pd = c[i] * ad_v;
#pragma unroll
            for (int off = 8; off; off >>= 1) {
                ps += __shfl_xor(ps, off);
                pd += __shfl_xor(pd, off);
            }
            if (lr == 0 && r < Nrows) {
                atomicAdd(&as_out[r], ps);
                atomicAdd(&ad_out[r], pd);
            }
        }
    }
}

// ---------------------------------------------------------------------------
// fp32 GEMM (dense / use_neighbors==0 path only).
// ---------------------------------------------------------------------------
__global__ __launch_bounds__(256) void gemm_xwt(
    const float* __restrict__ X, int lda, const float* __restrict__ W,
    const float* __restrict__ bias, float* __restrict__ out, int ldc,
    int Nrows, int M, int K, int relu,
    const int* __restrict__ flag, int wantFlag)
{
    if (((*flag != 0) ? 1 : 0) != wantFlag) return;

    const int z = blockIdx.z;
    X += (size_t)z * K;
    W += (size_t)z * M * K;
    if (bias) bias += (size_t)z * M;
    out += (size_t)z * M;

    __shared__ float As[16][68];
    __shared__ float Bs[16][68];

    const int t  = threadIdx.x;
    const int tx = t & 15;
    const int ty = t >> 4;
    const int rowBase = blockIdx.y * 64;
    const int colBase = blockIdx.x * 64;

    float acc[4][4];
#pragma unroll
    for (int i = 0; i < 4; i++)
#pragma unroll
        for (int j = 0; j < 4; j++) acc[i][j] = 0.f;

    const int r_ld = t >> 2;
    const int k_ld = (t & 3) * 4;

    for (int kt = 0; kt < K; kt += 16) {
        float4 av = make_float4(0.f, 0.f, 0.f, 0.f);
        int grow = rowBase + r_ld;
        if (grow < Nrows)
            av = *reinterpret_cast<const float4*>(&X[(size_t)grow * lda + kt + k_ld]);
        As[k_ld + 0][r_ld] = av.x;
        As[k_ld + 1][r_ld] = av.y;
        As[k_ld + 2][r_ld] = av.z;
        As[k_ld + 3][r_ld] = av.w;
        float4 bv = make_float4(0.f, 0.f, 0.f, 0.f);
        int gm = colBase + r_ld;
        if (gm < M)
            bv = *reinterpret_cast<const float4*>(&W[(size_t)gm * K + kt + k_ld]);
        Bs[k_ld + 0][r_ld] = bv.x;
        Bs[k_ld + 1][r_ld] = bv.y;
        Bs[k_ld + 2][r_ld] = bv.z;
        Bs[k_ld + 3][r_ld] = bv.w;
        __syncthreads();

#pragma unroll
        for (int kk = 0; kk < 16; ++kk) {
            const float4 a = *reinterpret_cast<const float4*>(&As[kk][ty * 4]);
            const float4 b = *reinterpret_cast<const float4*>(&Bs[kk][tx * 4]);
            acc[0][0] += a.x * b.x; acc[0][1] += a.x * b.y; acc[0][2] += a.x * b.z; acc[0][3] += a.x * b.w;
            acc[1][0] += a.y * b.x; acc[1][1] += a.y * b.y; acc[1][2] += a.y * b.z; acc[1][3] += a.y * b.w;
            acc[2][0] += a.z * b.x; acc[2][1] += a.z * b.y; acc[2][2] += a.z * b.z; acc[2][3] += a.z * b.w;
            acc[3][0] += a.w * b.x; acc[3][1] += a.w * b.y; acc[3][2] += a.w * b.z; acc[3][3] += a.w * b.w;
        }
        __syncthreads();
    }

#pragma unroll
    for (int i = 0; i < 4; i++) {
        int row = rowBase + ty * 4 + i;
        if (row >= Nrows) continue;
        int col0 = colBase + tx * 4;
        if (col0 >= M) continue;
        float4 v = make_float4(acc[i][0], acc[i][1], acc[i][2], acc[i][3]);
        if (bias) {
            v.x += bias[col0 + 0]; v.y += bias[col0 + 1];
            v.z += bias[col0 + 2]; v.w += bias[col0 + 3];
        }
        if (relu) {
            v.x = fmaxf(v.x, 0.f); v.y = fmaxf(v.y, 0.f);
            v.z = fmaxf(v.z, 0.f); v.w = fmaxf(v.w, 0.f);
        }
        *reinterpret_cast<float4*>(&out[(size_t)row * ldc + col0]) = v;
    }
}

// ---------------------------------------------------------------------------
// GAT aggregation of bf16 PROJECTED features (layers 2/4), +bias (+relu).
// fp32 out, optional bf16 shadow, optional fused NEXT-layer attention dots.
// ---------------------------------------------------------------------------
template <int HF, int RELU, int OUTB, int DOTS3>
__global__ __launch_bounds__(256) void gat_aggr_h(
    const unsigned short* __restrict__ hb, const float* __restrict__ as_,
    const float* __restrict__ ad_, const int* __restrict__ rowptr,
    const int* __restrict__ csr_src, const float* __restrict__ bias,
    float* __restrict__ out, unsigned short* __restrict__ outb,
    const float* __restrict__ u3s, const float* __restrict__ u3d,
    float* __restrict__ as3o, float* __restrict__ ad3o,
    const int* __restrict__ flag)
{
    if (*flag == 0) return;
    const int node = blockIdx.x * 4 + (threadIdx.x >> 6);
    const int lane = threadIdx.x & 63;
    if (node >= NODES) return;

    const int beg = rowptr[node], end = rowptr[node + 1];
    const int deg = end - beg;
    const float adv = ad_[node];

    float wl, mx, rden;
    int s_l = 0;
    const bool fast = (deg <= WAVE);

    if (fast) {
        int i = beg + lane;
        float e = -1e30f;
        if (i < end) {
            s_l = csr_src[i];
            e = lrelu(as_[s_l] + adv);
        }
        mx = e;
#pragma unroll
        for (int off = 32; off; off >>= 1)
            mx = fmaxf(mx, __shfl_xor(mx, off));
        wl = __expf(e - mx);
        float dn = wl;
#pragma unroll
        for (int off = 32; off; off >>= 1)
            dn += __shfl_xor(dn, off);
        rden = 1.f / dn;
    } else {
        mx = -1e30f;
        float den = 0.f;
        for (int i = beg + lane; i < end; i += WAVE) {
            int s = csr_src[i];
            mx = fmaxf(mx, lrelu(as_[s] + adv));
        }
#pragma unroll
        for (int off = 32; off; off >>= 1)
            mx = fmaxf(mx, __shfl_xor(mx, off));
        for (int i = beg + lane; i < end; i += WAVE) {
            int s = csr_src[i];
            den += __expf(lrelu(as_[s] + adv) - mx);
        }
#pragma unroll
        for (int off = 32; off; off >>= 1)
            den += __shfl_xor(den, off);
        rden = 1.f / den;
        wl = 0.f;
    }

    constexpr int LPG = HF / 8;
    constexpr int GR  = WAVE / LPG;
    const int esub = lane / LPG;
    const int c8   = lane % LPG;

    float acc[8];
#pragma unroll
    for (int j = 0; j < 8; j++) acc[j] = 0.f;

    if (fast) {
        const int iters = (deg + GR - 1) / GR;   // wave-uniform
        for (int it = 0; it < iters; ++it) {
            const int i = beg + it * GR + esub;
            const bool valid = (i < end);
            const int srcl = valid ? (i - beg) : 0;
            int s = __shfl(s_l, srcl);
            float w = __shfl(wl, srcl);
            if (valid) {
                uint4 q = *reinterpret_cast<const uint4*>(&hb[(size_t)s * HF + c8 * 8]);
                float v[8];
                unpack8(q, v);
#pragma unroll
                for (int j = 0; j < 8; j++) acc[j] += v[j] * w;
            }
        }
    } else {
        for (int i = beg + esub; i < end; i += GR) {
            int s = csr_src[i];
            float w = __expf(lrelu(as_[s] + adv) - mx);
            uint4 q = *reinterpret_cast<const uint4*>(&hb[(size_t)s * HF + c8 * 8]);
            float v[8];
            unpack8(q, v);
#pragma unroll
            for (int j = 0; j < 8; j++) acc[j] += v[j] * w;
        }
    }
#pragma unroll
    for (int off = LPG; off < WAVE; off <<= 1)
#pragma unroll
        for (int j = 0; j < 8; j++)
            acc[j] += __shfl_xor(acc[j], off);

    if (esub == 0) {
        const int col0 = c8 * 8;
        float o[8];
#pragma unroll
        for (int j = 0; j < 8; j++) {
            o[j] = acc[j] * rden + bias[col0 + j];
            if (RELU) o[j] = fmaxf(o[j], 0.f);
        }
        float4 o0 = make_float4(o[0], o[1], o[2], o[3]);
        float4 o1 = make_float4(o[4], o[5], o[6], o[7]);
        *reinterpret_cast<float4*>(&out[(size_t)node * HF + col0]) = o0;
        *reinterpret_cast<float4*>(&out[(size_t)node * HF + col0 + 4]) = o1;
        if (OUTB)
            *reinterpret_cast<uint4*>(&outb[(size_t)node * HF + col0]) = pack8(o);
        if (DOTS3) {
            float ps[2], pd[2];
#pragma unroll
            for (int h = 0; h < 2; h++) {
                float s1 = 0.f, s2 = 0.f;
#pragma unroll
                for (int j = 0; j < 8; j++) {
                    s1 += o[j] * u3s[h * HF + col0 + j];
                    s2 += o[j] * u3d[h * HF + col0 + j];
                }
                ps[h] = s1; pd[h] = s2;
            }
#pragma unroll
            for (int off = 1; off < LPG; off <<= 1) {
#pragma unroll
                for (int h = 0; h < 2; h++) {
                    ps[h] += __shfl_xor(ps[h], off);
                    pd[h] += __shfl_xor(pd[h], off);
                }
            }
            if (lane == 0) {
#pragma unroll
                for (int h = 0; h < 2; h++) {
                    as3o[node * 2 + h] = ps[h];
                    ad3o[node * 2 + h] = pd[h];
                }
            }
        }
    }
}

// ---------------------------------------------------------------------------
extern "C" void kernel_launch(void* const* d_in, const int* in_sizes, int n_in,
                              void* d_out, int out_size, void* d_ws, size_t ws_size,
                              hipStream_t stream)
{
    const float* x    = (const float*)d_in[0];
    const int*   ei   = (const int*)d_in[1];
    const int*   flag = (const int*)d_in[2];
    const float* W1 = (const float*)d_in[3];
    const float* as1 = (const float*)d_in[4];
    const float* ad1 = (const float*)d_in[5];
    const float* b1 = (const float*)d_in[6];
    const float* W2 = (const float*)d_in[7];
    const float* as2 = (const float*)d_in[8];
    const float* ad2 = (const float*)d_in[9];
    const float* b2 = (const float*)d_in[10];
    const float* W3 = (const float*)d_in[11];
    const float* as3 = (const float*)d_in[12];
    const float* ad3 = (const float*)d_in[13];
    const float* b3 = (const float*)d_in[14];
    const float* W4 = (const float*)d_in[15];
    const float* as4 = (const float*)d_in[16];
    const float* ad4 = (const float*)d_in[17];
    const float* b4 = (const float*)d_in[18];
    const float* el1w = (const float*)d_in[19];
    const float* el1b = (const float*)d_in[20];
    const float* el2w = (const float*)d_in[21];
    const float* el2b = (const float*)d_in[22];
    const float* dl1w = (const float*)d_in[23];
    const float* dl1b = (const float*)d_in[24];
    const float* dl2w = (const float*)d_in[25];
    const float* dl2b = (const float*)d_in[26];

    const int E_   = in_sizes[1] / 2;
    const int Etot = E_ + NODES;

    char* base = (char*)d_ws;
    size_t off = 0;
    auto carve = [&](size_t bytes) -> void* {
        void* p = base + off;
        off = (off + bytes + 255) & ~(size_t)255;
        return p;
    };
    float* T0  = (float*)carve((size_t)NODES * 128 * 4);   // dense intermediate
    float* A   = (float*)carve((size_t)NODES * 256 * 4);   // dense intermediate
    float* Bz  = (float*)carve((size_t)NODES * 32 * 4);    // z (fp32, dense + L2 out)
    float* asb = (float*)carve((size_t)NODES * 2 * 4);     // L1/L3 dots
    float* adb = (float*)carve((size_t)NODES * 2 * 4);
    float* as2b = (float*)carve((size_t)NODES * 4);        // L2 dots (atomic)
    float* ad2b = (float*)carve((size_t)NODES * 4);
    float* as4b = (float*)carve((size_t)NODES * 4);        // L4 dots (atomic)
    float* ad4b = (float*)carve((size_t)NODES * 4);
    float* u1s = (float*)carve(2 * 64 * 4);
    float* u1d = (float*)carve(2 * 64 * 4);
    float* u3s = (float*)carve(2 * 32 * 4);
    float* u3d = (float*)carve(2 * 32 * 4);
    unsigned short* xb   = (unsigned short*)carve((size_t)NODES * 64 * 2);   // bf16 x
    unsigned short* Ab   = (unsigned short*)carve((size_t)NODES * 256 * 2);  // bf16 L1/L3 out
    unsigned short* T1b  = (unsigned short*)carve((size_t)NODES * 64 * 2);   // bf16 h2/h4
    unsigned short* Bzb  = (unsigned short*)carve((size_t)NODES * 32 * 2);   // bf16 z
    unsigned short* wb1  = (unsigned short*)carve(256 * 64 * 2);
    unsigned short* wb2  = (unsigned short*)carve(32 * 256 * 2);
    unsigned short* wb3  = (unsigned short*)carve(256 * 32 * 2);
    unsigned short* wb4  = (unsigned short*)carve(64 * 256 * 2);
    int* deg    = (int*)carve((size_t)SCAN_CAP * 4);
    int* rowptr = (int*)carve((size_t)(SCAN_CAP + 1) * 4);
    int* rank   = (int*)carve((size_t)Etot * 4);
    int* csr    = (int*)carve((size_t)Etot * 4);
    (void)ws_size; (void)n_in; (void)out_size;

    float* outp = (float*)d_out;

    const int nodeBlocks = (NODES + 3) / 4;
    const int edgeBlocks = (Etot + 255) / 256;
    dim3 blk(256);
    const int rowTiles = (NODES + 63) / 64;   // 469

    // ---- chain head: zero deg, fused prep (+rank), scan, rank-scatter+attL1 ----
    hipMemsetAsync(deg, 0, (size_t)SCAN_CAP * 4, stream);
    prep2<<<2048, 256, 0, stream>>>(ei, E_, deg, rank, as2b, ad2b, as4b, ad4b,
                                    W1, wb1, W2, wb2, W3, wb3, W4, wb4,
                                    x, xb, as1, ad1, u1s, u1d,
                                    as3, ad3, u3s, u3d, flag);
    scan_deg<<<1, SCAN_T, 0, stream>>>(deg, rowptr, flag);
    scatter_attx<<<edgeBlocks + nodeBlocks, blk, 0, stream>>>(
        ei, rowptr, rank, csr, E_, edgeBlocks, x, u1s, u1d, asb, adb, flag);

    // ---- Layer 1: fused aggregate+project (64 -> 128 x 2 heads) + ReLU ----
    aggx_gemm<64, 2, 128><<<rowTiles, 1024, 0, stream>>>(
        xb, asb, adb, rowptr, csr, wb1, b1, Ab, flag);

    // ---- Layer 2: MFMA gemm (bf16 out + atomic dots); aggr fuses L3 dots ----
    gemm_mfma<256, 32, 1, 0, 1><<<dim3(rowTiles, 2, 1), blk, 0, stream>>>(
        Ab, 256, wb2, nullptr, T1b, 32, as2, ad2, as2b, ad2b, flag, NODES);
    gat_aggr_h<32, 0, 1, 1><<<nodeBlocks, blk, 0, stream>>>(
        T1b, as2b, ad2b, rowptr, csr, b2, Bz, Bzb, u3s, u3d, asb, adb, flag);

    // ---- Layer 3: fused aggregate+project (32 -> 128 x 2 heads) + ReLU ----
    aggx_gemm<32, 2, 128><<<rowTiles, 1024, 0, stream>>>(
        Bzb, asb, adb, rowptr, csr, wb3, b3, Ab, flag);

    // ---- Layer 4: MFMA gemm (bf16 out + atomic dots); aggr -> output ----
    gemm_mfma<256, 64, 1, 0, 1><<<dim3(rowTiles, 4, 1), blk, 0, stream>>>(
        Ab, 256, wb4, nullptr, T1b, 64, as4, ad4, as4b, ad4b, flag, NODES);
    gat_aggr_h<64, 0, 0, 0><<<nodeBlocks, blk, 0, stream>>>(
        T1b, as4b, ad4b, rowptr, csr, b4, outp, nullptr, nullptr, nullptr,
        nullptr, nullptr, flag);

    // ---- Dense path (use_neighbors == 0), fp32, unchanged ----
    gemm_xwt<<<dim3(2, rowTiles, 1), blk, 0, stream>>>(x,  64,  el1w, el1b, T0,   128, NODES, 128, 64, 1, flag, 0);
    gemm_xwt<<<dim3(1, rowTiles, 1), blk, 0, stream>>>(T0, 128, el2w, el2b, Bz,   32,  NODES, 32, 128, 0, flag, 0);
    gemm_xwt<<<dim3(2, rowTiles, 1), blk, 0, stream>>>(Bz, 32,  dl1w, dl1b, A,    128, NODES, 128, 32, 1, flag, 0);
    gemm_xwt<<<dim3(1, rowTiles, 1), blk, 0, stream>>>(A,  128, dl2w, dl2b, outp, 64,  NODES, 64, 128, 0, flag, 0);
}

// Round 13
// 325.884 us; speedup vs baseline: 1.1863x; 1.0379x over previous
//
#include <hip/hip_runtime.h>
#include <hip/hip_bf16.h>
#include <math.h>

#define NODES 30000
#define WAVE 64
#define SCAN_T 1024
#define SCAN_CH 32
#define SCAN_CAP (SCAN_T * SCAN_CH)   // 32768 >= NODES, branchless scan

typedef __attribute__((ext_vector_type(8))) short short8b;   // 8 bf16 (4 VGPRs)
typedef __attribute__((ext_vector_type(4))) float floatx4;   // MFMA C/D

static __device__ __forceinline__ float lrelu(float x) {
    return (x > 0.f) ? x : 0.2f * x;
}

// fp32 -> bf16 round-to-nearest-even
static __device__ __forceinline__ unsigned short f2bf(float f) {
    union { float f; unsigned u; } v; v.f = f;
    unsigned r = v.u + 0x7FFF + ((v.u >> 16) & 1);
    return (unsigned short)(r >> 16);
}

// unpack 8 bf16 (uint4) -> 8 floats
static __device__ __forceinline__ void unpack8(uint4 q, float* v) {
    v[0] = __uint_as_float(q.x << 16); v[1] = __uint_as_float(q.x & 0xFFFF0000u);
    v[2] = __uint_as_float(q.y << 16); v[3] = __uint_as_float(q.y & 0xFFFF0000u);
    v[4] = __uint_as_float(q.z << 16); v[5] = __uint_as_float(q.z & 0xFFFF0000u);
    v[6] = __uint_as_float(q.w << 16); v[7] = __uint_as_float(q.w & 0xFFFF0000u);
}

// pack 8 floats -> 8 bf16 (uint4)
static __device__ __forceinline__ uint4 pack8(const float* v) {
    uint4 p;
    p.x = (unsigned)f2bf(v[0]) | ((unsigned)f2bf(v[1]) << 16);
    p.y = (unsigned)f2bf(v[2]) | ((unsigned)f2bf(v[3]) << 16);
    p.z = (unsigned)f2bf(v[4]) | ((unsigned)f2bf(v[5]) << 16);
    p.w = (unsigned)f2bf(v[6]) | ((unsigned)f2bf(v[7]) << 16);
    return p;
}

// ---------------------------------------------------------------------------
// fold body: u[h,k] = sum_f att[h,f] * W[h*F+f, k]  (one block per (sel,h))
// ---------------------------------------------------------------------------
template <int HH, int F, int K>
static __device__ void fold_body(
    const float* __restrict__ W, const float* __restrict__ as_,
    const float* __restrict__ ad_, float* __restrict__ us,
    float* __restrict__ ud, int b, float* red)
{
    const int sel = b / HH;
    const int h   = b % HH;
    const float* att = sel ? ad_ : as_;
    float* uo = sel ? ud : us;

    constexpr int NG = 256 / K;
    const int k  = threadIdx.x % K;
    const int fg = threadIdx.x / K;

    float s = 0.f;
#pragma unroll
    for (int f = fg; f < F; f += NG)
        s += att[h * F + f] * W[(size_t)(h * F + f) * K + k];

    red[threadIdx.x] = s;
    __syncthreads();
    if (fg == 0) {
        float tot = s;
#pragma unroll
        for (int g = 1; g < NG; g++) tot += red[g * K + k];
        uo[h * K + k] = tot;
    }
}

// ---------------------------------------------------------------------------
// Fused prep (GAT path): count_deg atomics WITH rank capture (deg pre-zeroed
// via memset), zero dots buffers, cvt weights & x to bf16, fold L1/L3 att
// vectors (blocks 0-7 extra duty).
// ---------------------------------------------------------------------------
__global__ __launch_bounds__(256) void prep2(
    const int* __restrict__ ei, int E_, int* __restrict__ deg,
    int* __restrict__ rank,
    float* __restrict__ z0, float* __restrict__ z1,
    float* __restrict__ z2, float* __restrict__ z3,
    const float* __restrict__ W1, unsigned short* __restrict__ wb1,
    const float* __restrict__ W2, unsigned short* __restrict__ wb2,
    const float* __restrict__ W3, unsigned short* __restrict__ wb3,
    const float* __restrict__ W4, unsigned short* __restrict__ wb4,
    const float* __restrict__ x, unsigned short* __restrict__ xb,
    const float* __restrict__ as1, const float* __restrict__ ad1,
    float* __restrict__ u1s, float* __restrict__ u1d,
    const float* __restrict__ as3, const float* __restrict__ ad3,
    float* __restrict__ u3s, float* __restrict__ u3d,
    const int* __restrict__ flag)
{
    if (*flag == 0) return;
    __shared__ float red[256];
    const int tid = blockIdx.x * blockDim.x + threadIdx.x;
    const int stride = gridDim.x * blockDim.x;

    // degree count + per-edge rank (deg zeroed by preceding memset)
    const int tot = E_ + NODES;
    for (int e = tid; e < tot; e += stride) {
        int dst = (e < E_) ? ei[E_ + e] : (e - E_);
        rank[e] = atomicAdd(&deg[dst], 1);
    }
    for (int i = tid; i < NODES; i += stride) {
        z0[i] = 0.f; z1[i] = 0.f; z2[i] = 0.f; z3[i] = 0.f;
    }
    for (int i = tid; i < 256 * 64; i += stride) wb1[i] = f2bf(W1[i]);
    for (int i = tid; i < 32 * 256; i += stride) wb2[i] = f2bf(W2[i]);
    for (int i = tid; i < 256 * 32; i += stride) wb3[i] = f2bf(W3[i]);
    for (int i = tid; i < 64 * 256; i += stride) wb4[i] = f2bf(W4[i]);
    for (int i = tid; i < NODES * 64 / 4; i += stride) {
        float4 v = reinterpret_cast<const float4*>(x)[i];
        ushort4 o;
        o.x = f2bf(v.x); o.y = f2bf(v.y); o.z = f2bf(v.z); o.w = f2bf(v.w);
        reinterpret_cast<ushort4*>(xb)[i] = o;
    }

    // fold duty: blocks 0-3 = L1 (K=64), blocks 4-7 = L3 (K=32)
    if (blockIdx.x < 8) {
        __syncthreads();
        if (blockIdx.x < 4)
            fold_body<2, 128, 64>(W1, as1, ad1, u1s, u1d, blockIdx.x, red);
        else
            fold_body<2, 128, 32>(W3, as3, ad3, u3s, u3d, blockIdx.x - 4, red);
    }
}

// ---------------------------------------------------------------------------
// Branchless single-block scan over SCAN_CAP. Writes rowptr only.
// ---------------------------------------------------------------------------
__global__ __launch_bounds__(SCAN_T) void scan_deg(
    const int* __restrict__ deg, int* __restrict__ rowptr,
    const int* __restrict__ flag)
{
    if (*flag == 0) return;
    __shared__ int sums[SCAN_T];
    const int t = threadIdx.x;
    const int base = t * SCAN_CH;

    int v[SCAN_CH];
    const int4* dp = reinterpret_cast<const int4*>(deg + base);
#pragma unroll
    for (int j = 0; j < SCAN_CH / 4; j++) {
        int4 q = dp[j];
        v[4 * j + 0] = q.x; v[4 * j + 1] = q.y;
        v[4 * j + 2] = q.z; v[4 * j + 3] = q.w;
    }
    int s = 0;
#pragma unroll
    for (int j = 0; j < SCAN_CH; j++) s += v[j];
    sums[t] = s;
    __syncthreads();
    for (int off = 1; off < SCAN_T; off <<= 1) {
        int x = (t >= off) ? sums[t - off] : 0;
        __syncthreads();
        sums[t] += x;
        __syncthreads();
    }
    int run = sums[t] - s;
    if (t == 0) rowptr[0] = 0;
#pragma unroll
    for (int j = 0; j < SCAN_CH; j++) {
        run += v[j];
        rowptr[base + j + 1] = run;
    }
}

// ---------------------------------------------------------------------------
// Merged: rank-based scatter (NO atomics; blocks [0, eb)) + L1 attention
// dots (blocks [eb, ...)). The two halves are independent.
// ---------------------------------------------------------------------------
__global__ __launch_bounds__(256) void scatter_attx(
    const int* __restrict__ ei, const int* __restrict__ rowptr,
    const int* __restrict__ rank, int* __restrict__ csr_src, int E_, int eb,
    const float* __restrict__ x, const float* __restrict__ u1s,
    const float* __restrict__ u1d, float* __restrict__ as_out,
    float* __restrict__ ad_out, const int* __restrict__ flag)
{
    if (*flag == 0) return;
    const int b = blockIdx.x;
    if (b < eb) {
        int e = b * 256 + threadIdx.x;
        int tot = E_ + NODES;
        if (e >= tot) return;
        int src, dst;
        if (e < E_) { src = ei[e]; dst = ei[E_ + e]; }
        else        { src = e - E_; dst = src; }
        csr_src[rowptr[dst] + rank[e]] = src;
    } else {
        const int wid  = threadIdx.x >> 6;
        const int lane = threadIdx.x & 63;
        const int node = (b - eb) * 4 + wid;
        if (node >= NODES) return;
        float v = x[(size_t)node * 64 + lane];
        float ps[2], pd[2];
#pragma unroll
        for (int h = 0; h < 2; h++) {
            ps[h] = v * u1s[h * 64 + lane];
            pd[h] = v * u1d[h * 64 + lane];
        }
#pragma unroll
        for (int off = 32; off; off >>= 1) {
#pragma unroll
            for (int h = 0; h < 2; h++) {
                ps[h] += __shfl_xor(ps[h], off);
                pd[h] += __shfl_xor(pd[h], off);
            }
        }
        if (lane == 0) {
#pragma unroll
            for (int h = 0; h < 2; h++) {
                as_out[node * 2 + h] = ps[h];
                ad_out[node * 2 + h] = pd[h];
            }
        }
    }
}

// ---------------------------------------------------------------------------
// FUSED aggregate+project (layers 1/3): 16 nodes per 1024-thread block.
// Phase A: ONE WAVE PER NODE (full 30000-wave parallelism) — softmax with
// one edge/lane (weight & src index in registers, shfl-fetched, wave-uniform
// gather loop) -> padded LDS tile [16][HH*K+8].
// Phase B: 16 waves = 16 col-tiles; each wave one 16x16x(K) MFMA over the
// block's 16 rows, +bias+relu, bf16 out.
// ---------------------------------------------------------------------------
template <int K, int HH, int M>
__global__ __launch_bounds__(1024) void aggx_gemm(
    const unsigned short* __restrict__ xb,
    const float* __restrict__ as_, const float* __restrict__ ad_,
    const int* __restrict__ rowptr, const int* __restrict__ csr_src,
    const unsigned short* __restrict__ Wb, const float* __restrict__ bias,
    unsigned short* __restrict__ outb, const int* __restrict__ flag)
{
    if (*flag == 0) return;
    constexpr int LDSW = HH * K + 8;          // pad: odd # of 4-dword groups
    __shared__ unsigned short agg[16][LDSW];

    const int wid  = threadIdx.x >> 6;        // 0..15
    const int lane = threadIdx.x & 63;
    const int nb   = blockIdx.x * 16;

    constexpr int LPG = K / 8;                // lanes per edge (8 bf16 each)
    constexpr int GR  = WAVE / LPG;           // edges in flight per iter
    const int esub = lane / LPG;
    const int c8   = lane % LPG;

    // ---- Phase A: one node per wave ----
    const int node = nb + wid;
    {
        const int beg = rowptr[node], end = rowptr[node + 1];
        const int deg = end - beg;

        float adv[HH];
#pragma unroll
        for (int h = 0; h < HH; h++) adv[h] = ad_[node * HH + h];

        float wl[HH], mx[HH], rden[HH];
        int s_l = 0;
        const bool fast = (deg <= WAVE);

        if (fast) {
            float e[HH];
            int i = beg + lane;
            if (i < end) {
                s_l = csr_src[i];
#pragma unroll
                for (int h = 0; h < HH; h++)
                    e[h] = lrelu(as_[s_l * HH + h] + adv[h]);
            } else {
#pragma unroll
                for (int h = 0; h < HH; h++) e[h] = -1e30f;
            }
#pragma unroll
            for (int h = 0; h < HH; h++) {
                mx[h] = e[h];
#pragma unroll
                for (int off = 32; off; off >>= 1)
                    mx[h] = fmaxf(mx[h], __shfl_xor(mx[h], off));
                float ex = __expf(e[h] - mx[h]);
                wl[h] = ex;
                float dn = ex;
#pragma unroll
                for (int off = 32; off; off >>= 1)
                    dn += __shfl_xor(dn, off);
                rden[h] = 1.f / dn;
            }
        } else {
            float den[HH];
#pragma unroll
            for (int h = 0; h < HH; h++) { mx[h] = -1e30f; den[h] = 0.f; }
            for (int i = beg + lane; i < end; i += WAVE) {
                int s = csr_src[i];
#pragma unroll
                for (int h = 0; h < HH; h++)
                    mx[h] = fmaxf(mx[h], lrelu(as_[s * HH + h] + adv[h]));
            }
#pragma unroll
            for (int h = 0; h < HH; h++)
#pragma unroll
                for (int off = 32; off; off >>= 1)
                    mx[h] = fmaxf(mx[h], __shfl_xor(mx[h], off));
            for (int i = beg + lane; i < end; i += WAVE) {
                int s = csr_src[i];
#pragma unroll
                for (int h = 0; h < HH; h++)
                    den[h] += __expf(lrelu(as_[s * HH + h] + adv[h]) - mx[h]);
            }
#pragma unroll
            for (int h = 0; h < HH; h++) {
#pragma unroll
                for (int off = 32; off; off >>= 1)
                    den[h] += __shfl_xor(den[h], off);
                rden[h] = 1.f / den[h];
            }
        }

        float acc[HH][8];
#pragma unroll
        for (int h = 0; h < HH; h++)
#pragma unroll
            for (int j = 0; j < 8; j++) acc[h][j] = 0.f;

        if (fast) {
            const int iters = (deg + GR - 1) / GR;   // wave-uniform
            for (int it = 0; it < iters; ++it) {
                const int i = beg + it * GR + esub;
                const bool valid = (i < end);
                const int srcl = valid ? (i - beg) : 0;
                int s = __shfl(s_l, srcl);           // index from register
                float w[HH];
#pragma unroll
                for (int h = 0; h < HH; h++)
                    w[h] = __shfl(wl[h], srcl);
                if (valid) {
                    uint4 q = *reinterpret_cast<const uint4*>(&xb[(size_t)s * K + c8 * 8]);
                    float v[8];
                    unpack8(q, v);
#pragma unroll
                    for (int h = 0; h < HH; h++)
#pragma unroll
                        for (int j = 0; j < 8; j++)
                            acc[h][j] += v[j] * w[h];
                }
            }
        } else {
            for (int i = beg + esub; i < end; i += GR) {
                int s = csr_src[i];
                float w[HH];
#pragma unroll
                for (int h = 0; h < HH; h++)
                    w[h] = __expf(lrelu(as_[s * HH + h] + adv[h]) - mx[h]);
                uint4 q = *reinterpret_cast<const uint4*>(&xb[(size_t)s * K + c8 * 8]);
                float v[8];
                unpack8(q, v);
#pragma unroll
                for (int h = 0; h < HH; h++)
#pragma unroll
                    for (int j = 0; j < 8; j++)
                        acc[h][j] += v[j] * w[h];
            }
        }
#pragma unroll
        for (int off = LPG; off < WAVE; off <<= 1)
#pragma unroll
            for (int h = 0; h < HH; h++)
#pragma unroll
                for (int j = 0; j < 8; j++)
                    acc[h][j] += __shfl_xor(acc[h][j], off);

        if (esub == 0) {
#pragma unroll
            for (int h = 0; h < HH; h++) {
                float o[8];
#pragma unroll
                for (int j = 0; j < 8; j++) o[j] = acc[h][j] * rden[h];
                *reinterpret_cast<uint4*>(&agg[wid][h * K + c8 * 8]) = pack8(o);
            }
        }
    }
    __syncthreads();

    // ---- Phase B: 16 waves = 16 col-tiles, one 16x16 MFMA tile each ----
    constexpr int KC   = K / 32;
    constexpr int CTPH = M / 16;              // col tiles per head (8)
    const int lr = lane & 15;
    const int lk = (lane >> 4) * 8;
    const int z  = wid / CTPH;                // head
    const int mc = (wid % CTPH) * 16;         // col base within head

    const unsigned short* bp = Wb + (size_t)(z * M + mc + lr) * K + lk;
    short8b b[KC];
#pragma unroll
    for (int kc = 0; kc < KC; kc++)
        b[kc] = *reinterpret_cast<const short8b*>(bp + kc * 32);

    short8b a[KC];
#pragma unroll
    for (int kc = 0; kc < KC; kc++)
        a[kc] = *reinterpret_cast<const short8b*>(&agg[lr][z * K + lk + kc * 32]);

    floatx4 c = {0.f, 0.f, 0.f, 0.f};
#pragma unroll
    for (int kc = 0; kc < KC; kc++)
        c = __builtin_amdgcn_mfma_f32_16x16x32_bf16(a[kc], b[kc], c, 0, 0, 0);

    const int colg = z * M + mc + lr;
    const float bv = bias[colg];
#pragma unroll
    for (int i = 0; i < 4; i++) {
        int r = nb + (lane >> 4) * 4 + i;
        float v = fmaxf(c[i] + bv, 0.f);      // L1/L3 always ReLU
        outb[(size_t)r * (HH * M) + colg] = f2bf(v);
    }
}

// ---------------------------------------------------------------------------
// MFMA GEMM (layers 2/4): bf16 in, fp32 acc, bf16 out + fused atomic dots.
// ---------------------------------------------------------------------------
template <int K, int M, int OUT_BF16, int RELU, int DOTS>
__global__ __launch_bounds__(256) void gemm_mfma(
    const unsigned short* __restrict__ Xb, int ldx,
    const unsigned short* __restrict__ Wb,
    const float* __restrict__ bias,
    void* __restrict__ outv, int ldc,
    const float* __restrict__ att_s, const float* __restrict__ att_d,
    float* __restrict__ as_out, float* __restrict__ ad_out,
    const int* __restrict__ flag, int Nrows)
{
    if (*flag == 0) return;
    constexpr int KC = K / 32;
    const int w    = threadIdx.x >> 6;
    const int lane = threadIdx.x & 63;
    const int z    = blockIdx.z;
    const int ct   = blockIdx.y;
    const int rowBase = blockIdx.x * 64 + w * 16;

    const int lr = lane & 15;
    const int lk = (lane >> 4) * 8;

    const int arow = min(rowBase + lr, Nrows - 1);
    const unsigned short* ap = Xb + (size_t)arow * ldx + z * K + lk;
    short8b a[KC];
#pragma unroll
    for (int kc = 0; kc < KC; kc++)
        a[kc] = *reinterpret_cast<const short8b*>(ap + kc * 32);

    const unsigned short* bp = Wb + (size_t)(z * M + ct * 16 + lr) * K + lk;
    short8b b[KC];
#pragma unroll
    for (int kc = 0; kc < KC; kc++)
        b[kc] = *reinterpret_cast<const short8b*>(bp + kc * 32);

    floatx4 c = {0.f, 0.f, 0.f, 0.f};
#pragma unroll
    for (int kc = 0; kc < KC; kc++)
        c = __builtin_amdgcn_mfma_f32_16x16x32_bf16(a[kc], b[kc], c, 0, 0, 0);

    const int colg = z * M + ct * 16 + lr;
    const float bv = bias ? bias[colg] : 0.f;

#pragma unroll
    for (int i = 0; i < 4; i++) {
        int r = rowBase + (lane >> 4) * 4 + i;
        float v = c[i] + bv;
        if (RELU) v = fmaxf(v, 0.f);
        if (r < Nrows) {
            if (OUT_BF16)
                ((unsigned short*)outv)[(size_t)r * ldc + colg] = f2bf(v);
            else
                ((float*)outv)[(size_t)r * ldc + colg] = v;
        }
    }

    if (DOTS) {
        const float as_v = att_s[colg];
        const float ad_v = att_d[colg];
#pragma unroll
        for (int i = 0; i < 4; i++) {
            int r = rowBase + (lane >> 4) * 4 + i;
            float ps = c[i] * as_v;
            float pd = c[i] * ad_v;
#pragma unroll
            for (int off = 8; off; off >>= 1) {
                ps += __shfl_xor(ps, off);
                pd += __shfl_xor(pd, off);
            }
            if (lr == 0 && r < Nrows) {
                atomicAdd(&as_out[r], ps);
                atomicAdd(&ad_out[r], pd);
            }
        }
    }
}

// ---------------------------------------------------------------------------
// fp32 GEMM (dense / use_neighbors==0 path only).
// ---------------------------------------------------------------------------
__global__ __launch_bounds__(256) void gemm_xwt(
    const float* __restrict__ X, int lda, const float* __restrict__ W,
    const float* __restrict__ bias, float* __restrict__ out, int ldc,
    int Nrows, int M, int K, int relu,
    const int* __restrict__ flag, int wantFlag)
{
    if (((*flag != 0) ? 1 : 0) != wantFlag) return;

    const int z = blockIdx.z;
    X += (size_t)z * K;
    W += (size_t)z * M * K;
    if (bias) bias += (size_t)z * M;
    out += (size_t)z * M;

    __shared__ float As[16][68];
    __shared__ float Bs[16][68];

    const int t  = threadIdx.x;
    const int tx = t & 15;
    const int ty = t >> 4;
    const int rowBase = blockIdx.y * 64;
    const int colBase = blockIdx.x * 64;

    float acc[4][4];
#pragma unroll
    for (int i = 0; i < 4; i++)
#pragma unroll
        for (int j = 0; j < 4; j++) acc[i][j] = 0.f;

    const int r_ld = t >> 2;
    const int k_ld = (t & 3) * 4;

    for (int kt = 0; kt < K; kt += 16) {
        float4 av = make_float4(0.f, 0.f, 0.f, 0.f);
        int grow = rowBase + r_ld;
        if (grow < Nrows)
            av = *reinterpret_cast<const float4*>(&X[(size_t)grow * lda + kt + k_ld]);
        As[k_ld + 0][r_ld] = av.x;
        As[k_ld + 1][r_ld] = av.y;
        As[k_ld + 2][r_ld] = av.z;
        As[k_ld + 3][r_ld] = av.w;
        float4 bv = make_float4(0.f, 0.f, 0.f, 0.f);
        int gm = colBase + r_ld;
        if (gm < M)
            bv = *reinterpret_cast<const float4*>(&W[(size_t)gm * K + kt + k_ld]);
        Bs[k_ld + 0][r_ld] = bv.x;
        Bs[k_ld + 1][r_ld] = bv.y;
        Bs[k_ld + 2][r_ld] = bv.z;
        Bs[k_ld + 3][r_ld] = bv.w;
        __syncthreads();

#pragma unroll
        for (int kk = 0; kk < 16; ++kk) {
            const float4 a = *reinterpret_cast<const float4*>(&As[kk][ty * 4]);
            const float4 b = *reinterpret_cast<const float4*>(&Bs[kk][tx * 4]);
            acc[0][0] += a.x * b.x; acc[0][1] += a.x * b.y; acc[0][2] += a.x * b.z; acc[0][3] += a.x * b.w;
            acc[1][0] += a.y * b.x; acc[1][1] += a.y * b.y; acc[1][2] += a.y * b.z; acc[1][3] += a.y * b.w;
            acc[2][0] += a.z * b.x; acc[2][1] += a.z * b.y; acc[2][2] += a.z * b.z; acc[2][3] += a.z * b.w;
            acc[3][0] += a.w * b.x; acc[3][1] += a.w * b.y; acc[3][2] += a.w * b.z; acc[3][3] += a.w * b.w;
        }
        __syncthreads();
    }

#pragma unroll
    for (int i = 0; i < 4; i++) {
        int row = rowBase + ty * 4 + i;
        if (row >= Nrows) continue;
        int col0 = colBase + tx * 4;
        if (col0 >= M) continue;
        float4 v = make_float4(acc[i][0], acc[i][1], acc[i][2], acc[i][3]);
        if (bias) {
            v.x += bias[col0 + 0]; v.y += bias[col0 + 1];
            v.z += bias[col0 + 2]; v.w += bias[col0 + 3];
        }
        if (relu) {
            v.x = fmaxf(v.x, 0.f); v.y = fmaxf(v.y, 0.f);
            v.z = fmaxf(v.z, 0.f); v.w = fmaxf(v.w, 0.f);
        }
        *reinterpret_cast<float4*>(&out[(size_t)row * ldc + col0]) = v;
    }
}

// ---------------------------------------------------------------------------
// GAT aggregation of bf16 PROJECTED features (layers 2/4), +bias (+relu).
// fp32 out, optional bf16 shadow, optional fused NEXT-layer attention dots.
// ---------------------------------------------------------------------------
template <int HF, int RELU, int OUTB, int DOTS3>
__global__ __launch_bounds__(256) void gat_aggr_h(
    const unsigned short* __restrict__ hb, const float* __restrict__ as_,
    const float* __restrict__ ad_, const int* __restrict__ rowptr,
    const int* __restrict__ csr_src, const float* __restrict__ bias,
    float* __restrict__ out, unsigned short* __restrict__ outb,
    const float* __restrict__ u3s, const float* __restrict__ u3d,
    float* __restrict__ as3o, float* __restrict__ ad3o,
    const int* __restrict__ flag)
{
    if (*flag == 0) return;
    const int node = blockIdx.x * 4 + (threadIdx.x >> 6);
    const int lane = threadIdx.x & 63;
    if (node >= NODES) return;

    const int beg = rowptr[node], end = rowptr[node + 1];
    const int deg = end - beg;
    const float adv = ad_[node];

    float wl, mx, rden;
    int s_l = 0;
    const bool fast = (deg <= WAVE);

    if (fast) {
        int i = beg + lane;
        float e = -1e30f;
        if (i < end) {
            s_l = csr_src[i];
            e = lrelu(as_[s_l] + adv);
        }
        mx = e;
#pragma unroll
        for (int off = 32; off; off >>= 1)
            mx = fmaxf(mx, __shfl_xor(mx, off));
        wl = __expf(e - mx);
        float dn = wl;
#pragma unroll
        for (int off = 32; off; off >>= 1)
            dn += __shfl_xor(dn, off);
        rden = 1.f / dn;
    } else {
        mx = -1e30f;
        float den = 0.f;
        for (int i = beg + lane; i < end; i += WAVE) {
            int s = csr_src[i];
            mx = fmaxf(mx, lrelu(as_[s] + adv));
        }
#pragma unroll
        for (int off = 32; off; off >>= 1)
            mx = fmaxf(mx, __shfl_xor(mx, off));
        for (int i = beg + lane; i < end; i += WAVE) {
            int s = csr_src[i];
            den += __expf(lrelu(as_[s] + adv) - mx);
        }
#pragma unroll
        for (int off = 32; off; off >>= 1)
            den += __shfl_xor(den, off);
        rden = 1.f / den;
        wl = 0.f;
    }

    constexpr int LPG = HF / 8;
    constexpr int GR  = WAVE / LPG;
    const int esub = lane / LPG;
    const int c8   = lane % LPG;

    float acc[8];
#pragma unroll
    for (int j = 0; j < 8; j++) acc[j] = 0.f;

    if (fast) {
        const int iters = (deg + GR - 1) / GR;   // wave-uniform
        for (int it = 0; it < iters; ++it) {
            const int i = beg + it * GR + esub;
            const bool valid = (i < end);
            const int srcl = valid ? (i - beg) : 0;
            int s = __shfl(s_l, srcl);
            float w = __shfl(wl, srcl);
            if (valid) {
                uint4 q = *reinterpret_cast<const uint4*>(&hb[(size_t)s * HF + c8 * 8]);
                float v[8];
                unpack8(q, v);
#pragma unroll
                for (int j = 0; j < 8; j++) acc[j] += v[j] * w;
            }
        }
    } else {
        for (int i = beg + esub; i < end; i += GR) {
            int s = csr_src[i];
            float w = __expf(lrelu(as_[s] + adv) - mx);
            uint4 q = *reinterpret_cast<const uint4*>(&hb[(size_t)s * HF + c8 * 8]);
            float v[8];
            unpack8(q, v);
#pragma unroll
            for (int j = 0; j < 8; j++) acc[j] += v[j] * w;
        }
    }
#pragma unroll
    for (int off = LPG; off < WAVE; off <<= 1)
#pragma unroll
        for (int j = 0; j < 8; j++)
            acc[j] += __shfl_xor(acc[j], off);

    if (esub == 0) {
        const int col0 = c8 * 8;
        float o[8];
#pragma unroll
        for (int j = 0; j < 8; j++) {
            o[j] = acc[j] * rden + bias[col0 + j];
            if (RELU) o[j] = fmaxf(o[j], 0.f);
        }
        float4 o0 = make_float4(o[0], o[1], o[2], o[3]);
        float4 o1 = make_float4(o[4], o[5], o[6], o[7]);
        *reinterpret_cast<float4*>(&out[(size_t)node * HF + col0]) = o0;
        *reinterpret_cast<float4*>(&out[(size_t)node * HF + col0 + 4]) = o1;
        if (OUTB)
            *reinterpret_cast<uint4*>(&outb[(size_t)node * HF + col0]) = pack8(o);
        if (DOTS3) {
            float ps[2], pd[2];
#pragma unroll
            for (int h = 0; h < 2; h++) {
                float s1 = 0.f, s2 = 0.f;
#pragma unroll
                for (int j = 0; j < 8; j++) {
                    s1 += o[j] * u3s[h * HF + col0 + j];
                    s2 += o[j] * u3d[h * HF + col0 + j];
                }
                ps[h] = s1; pd[h] = s2;
            }
#pragma unroll
            for (int off = 1; off < LPG; off <<= 1) {
#pragma unroll
                for (int h = 0; h < 2; h++) {
                    ps[h] += __shfl_xor(ps[h], off);
                    pd[h] += __shfl_xor(pd[h], off);
                }
            }
            if (lane == 0) {
#pragma unroll
                for (int h = 0; h < 2; h++) {
                    as3o[node * 2 + h] = ps[h];
                    ad3o[node * 2 + h] = pd[h];
                }
            }
        }
    }
}

// ---------------------------------------------------------------------------
extern "C" void kernel_launch(void* const* d_in, const int* in_sizes, int n_in,
                              void* d_out, int out_size, void* d_ws, size_t ws_size,
                              hipStream_t stream)
{
    const float* x    = (const float*)d_in[0];
    const int*   ei   = (const int*)d_in[1];
    const int*   flag = (const int*)d_in[2];
    const float* W1 = (const float*)d_in[3];
    const float* as1 = (const float*)d_in[4];
    const float* ad1 = (const float*)d_in[5];
    const float* b1 = (const float*)d_in[6];
    const float* W2 = (const float*)d_in[7];
    const float* as2 = (const float*)d_in[8];
    const float* ad2 = (const float*)d_in[9];
    const float* b2 = (const float*)d_in[10];
    const float* W3 = (const float*)d_in[11];
    const float* as3 = (const float*)d_in[12];
    const float* ad3 = (const float*)d_in[13];
    const float* b3 = (const float*)d_in[14];
    const float* W4 = (const float*)d_in[15];
    const float* as4 = (const float*)d_in[16];
    const float* ad4 = (const float*)d_in[17];
    const float* b4 = (const float*)d_in[18];
    const float* el1w = (const float*)d_in[19];
    const float* el1b = (const float*)d_in[20];
    const float* el2w = (const float*)d_in[21];
    const float* el2b = (const float*)d_in[22];
    const float* dl1w = (const float*)d_in[23];
    const float* dl1b = (const float*)d_in[24];
    const float* dl2w = (const float*)d_in[25];
    const float* dl2b = (const float*)d_in[26];

    const int E_   = in_sizes[1] / 2;
    const int Etot = E_ + NODES;

    char* base = (char*)d_ws;
    size_t off = 0;
    auto carve = [&](size_t bytes) -> void* {
        void* p = base + off;
        off = (off + bytes + 255) & ~(size_t)255;
        return p;
    };
    float* T0  = (float*)carve((size_t)NODES * 128 * 4);   // dense intermediate
    float* A   = (float*)carve((size_t)NODES * 256 * 4);   // dense intermediate
    float* Bz  = (float*)carve((size_t)NODES * 32 * 4);    // z (fp32, dense + L2 out)
    float* asb = (float*)carve((size_t)NODES * 2 * 4);     // L1/L3 dots
    float* adb = (float*)carve((size_t)NODES * 2 * 4);
    float* as2b = (float*)carve((size_t)NODES * 4);        // L2 dots (atomic)
    float* ad2b = (float*)carve((size_t)NODES * 4);
    float* as4b = (float*)carve((size_t)NODES * 4);        // L4 dots (atomic)
    float* ad4b = (float*)carve((size_t)NODES * 4);
    float* u1s = (float*)carve(2 * 64 * 4);
    float* u1d = (float*)carve(2 * 64 * 4);
    float* u3s = (float*)carve(2 * 32 * 4);
    float* u3d = (float*)carve(2 * 32 * 4);
    unsigned short* xb   = (unsigned short*)carve((size_t)NODES * 64 * 2);   // bf16 x
    unsigned short* Ab   = (unsigned short*)carve((size_t)NODES * 256 * 2);  // bf16 L1/L3 out
    unsigned short* T1b  = (unsigned short*)carve((size_t)NODES * 64 * 2);   // bf16 h2/h4
    unsigned short* Bzb  = (unsigned short*)carve((size_t)NODES * 32 * 2);   // bf16 z
    unsigned short* wb1  = (unsigned short*)carve(256 * 64 * 2);
    unsigned short* wb2  = (unsigned short*)carve(32 * 256 * 2);
    unsigned short* wb3  = (unsigned short*)carve(256 * 32 * 2);
    unsigned short* wb4  = (unsigned short*)carve(64 * 256 * 2);
    int* deg    = (int*)carve((size_t)SCAN_CAP * 4);
    int* rowptr = (int*)carve((size_t)(SCAN_CAP + 1) * 4);
    int* rank   = (int*)carve((size_t)Etot * 4);
    int* csr    = (int*)carve((size_t)Etot * 4);
    (void)ws_size; (void)n_in; (void)out_size;

    float* outp = (float*)d_out;

    const int nodeBlocks = (NODES + 3) / 4;
    const int edgeBlocks = (Etot + 255) / 256;
    dim3 blk(256);
    const int rowTiles = (NODES + 63) / 64;   // 469 (dense path, L2/L4 gemm)
    const int tile16   = (NODES + 15) / 16;   // 1875 (fused aggx_gemm)

    // ---- chain head: zero deg, fused prep (+rank), scan, rank-scatter+attL1 ----
    hipMemsetAsync(deg, 0, (size_t)SCAN_CAP * 4, stream);
    prep2<<<2048, 256, 0, stream>>>(ei, E_, deg, rank, as2b, ad2b, as4b, ad4b,
                                    W1, wb1, W2, wb2, W3, wb3, W4, wb4,
                                    x, xb, as1, ad1, u1s, u1d,
                                    as3, ad3, u3s, u3d, flag);
    scan_deg<<<1, SCAN_T, 0, stream>>>(deg, rowptr, flag);
    scatter_attx<<<edgeBlocks + nodeBlocks, blk, 0, stream>>>(
        ei, rowptr, rank, csr, E_, edgeBlocks, x, u1s, u1d, asb, adb, flag);

    // ---- Layer 1: fused aggregate+project (64 -> 128 x 2 heads) + ReLU ----
    aggx_gemm<64, 2, 128><<<tile16, 1024, 0, stream>>>(
        xb, asb, adb, rowptr, csr, wb1, b1, Ab, flag);

    // ---- Layer 2: MFMA gemm (bf16 out + atomic dots); aggr fuses L3 dots ----
    gemm_mfma<256, 32, 1, 0, 1><<<dim3(rowTiles, 2, 1), blk, 0, stream>>>(
        Ab, 256, wb2, nullptr, T1b, 32, as2, ad2, as2b, ad2b, flag, NODES);
    gat_aggr_h<32, 0, 1, 1><<<nodeBlocks, blk, 0, stream>>>(
        T1b, as2b, ad2b, rowptr, csr, b2, Bz, Bzb, u3s, u3d, asb, adb, flag);

    // ---- Layer 3: fused aggregate+project (32 -> 128 x 2 heads) + ReLU ----
    aggx_gemm<32, 2, 128><<<tile16, 1024, 0, stream>>>(
        Bzb, asb, adb, rowptr, csr, wb3, b3, Ab, flag);

    // ---- Layer 4: MFMA gemm (bf16 out + atomic dots); aggr -> output ----
    gemm_mfma<256, 64, 1, 0, 1><<<dim3(rowTiles, 4, 1), blk, 0, stream>>>(
        Ab, 256, wb4, nullptr, T1b, 64, as4, ad4, as4b, ad4b, flag, NODES);
    gat_aggr_h<64, 0, 0, 0><<<nodeBlocks, blk, 0, stream>>>(
        T1b, as4b, ad4b, rowptr, csr, b4, outp, nullptr, nullptr, nullptr,
        nullptr, nullptr, flag);

    // ---- Dense path (use_neighbors == 0), fp32, unchanged ----
    gemm_xwt<<<dim3(2, rowTiles, 1), blk, 0, stream>>>(x,  64,  el1w, el1b, T0,   128, NODES, 128, 64, 1, flag, 0);
    gemm_xwt<<<dim3(1, rowTiles, 1), blk, 0, stream>>>(T0, 128, el2w, el2b, Bz,   32,  NODES, 32, 128, 0, flag, 0);
    gemm_xwt<<<dim3(2, rowTiles, 1), blk, 0, stream>>>(Bz, 32,  dl1w, dl1b, A,    128, NODES, 128, 32, 1, flag, 0);
    gemm_xwt<<<dim3(1, rowTiles, 1), blk, 0, stream>>>(A,  128, dl2w, dl2b, outp, 64,  NODES, 64, 128, 0, flag, 0);
}